// Round 1
// baseline (3130.018 us; speedup 1.0000x reference)
//
#include <hip/hip_runtime.h>
#include <hip/hip_bf16.h>

#define N_NODES 50000
#define N_EDGES 800000
#define NF      64
#define NG      50
#define NPG     (N_NODES / NG)   // 1000 nodes per graph

// ---------------------------------------------------------------------------
// degree histogram: deg[col[e]] += 1
__global__ void k_deg(const int* __restrict__ col, float* __restrict__ deg) {
    int e = blockIdx.x * 256 + threadIdx.x;
    if (e < N_EDGES) atomicAdd(&deg[col[e]], 1.0f);
}

// max(deg) -> dmax (float bits via int atomicMax; deg > 0 so bit-compare is valid)
__global__ void k_degmax(const float* __restrict__ deg, float* __restrict__ dmax) {
    int i = blockIdx.x * 256 + threadIdx.x;
    float m = (i < N_NODES) ? deg[i] : 0.f;
    for (int off = 32; off; off >>= 1) m = fmaxf(m, __shfl_xor(m, off, 64));
    if ((threadIdx.x & 63) == 0) atomicMax((int*)dmax, __float_as_int(m));
}

// cur = relu(x @ W_init) [N,64];  h = relu(x @ W_e1) [N,63] stored padded [N,64] (lane63 = 0)
__global__ void k_init(const float* __restrict__ x, const float* __restrict__ Wi,
                       const float* __restrict__ We1,
                       float* __restrict__ cur, float* __restrict__ h) {
    int idx = blockIdx.x * 256 + threadIdx.x;
    int node = idx >> 6, f = idx & 63;
    if (node >= N_NODES) return;
    float4 xv = ((const float4*)x)[node];
    float c = xv.x * Wi[f] + xv.y * Wi[64 + f] + xv.z * Wi[128 + f] + xv.w * Wi[192 + f];
    cur[idx] = fmaxf(c, 0.f);
    float hv = 0.f;
    if (f < 63) {
        hv = xv.x * We1[f] + xv.y * We1[63 + f] + xv.z * We1[126 + f] + xv.w * We1[189 + f];
        hv = fmaxf(hv, 0.f);
    }
    h[idx] = hv;
}

// dst[col[e]] += src[row[e]]  (64 feats; 16 lanes/edge x float4)
__global__ void k_scatter(const float* __restrict__ src, float* __restrict__ dst,
                          const int* __restrict__ row, const int* __restrict__ col) {
    int idx = blockIdx.x * 256 + threadIdx.x;
    int e = idx >> 4;
    if (e >= N_EDGES) return;
    int c4 = (idx & 15) << 2;
    int r = row[e], c = col[e];
    float4 v = *(const float4*)(src + r * 64 + c4);
    float* d = dst + c * 64 + c4;
    atomicAdd(d + 0, v.x); atomicAdd(d + 1, v.y);
    atomicAdd(d + 2, v.z); atomicAdd(d + 3, v.w);
}

// edge_emb = relu( [deg_inv*agg(63) | deg/degmax(1)] @ W_e2 )
__global__ __launch_bounds__(256) void k_edge_emb(
        const float* __restrict__ agg, const float* __restrict__ deg,
        const float* __restrict__ dmax, const float* __restrict__ We2,
        float* __restrict__ ee) {
    __shared__ float W[64 * 64];
    __shared__ float Y[4][64];
    int t = threadIdx.x;
    for (int i = t; i < 4096; i += 256) W[i] = We2[i];
    __syncthreads();
    int wv = t >> 6, lane = t & 63;
    float idm = 1.0f / dmax[0];
    int wg = blockIdx.x * 4 + wv, nw = gridDim.x * 4;
    for (int node = wg; node < N_NODES; node += nw) {
        float d = deg[node];
        float y = (lane < 63) ? agg[node * 64 + lane] * (1.0f / d) : d * idm;
        Y[wv][lane] = y;                       // wave-synchronous: no barrier needed
        float acc = 0.f;
#pragma unroll 16
        for (int k = 0; k < 64; k++) acc = fmaf(Y[wv][k], W[k * 64 + lane], acc);
        ee[node * 64 + lane] = fmaxf(acc, 0.f);
    }
}

// one MPNN layer: msg = relu([deg_inv*agg | ee] @ Wm); out = relu([cur | msg] @ Wu)
// wave processes 4 nodes; weights in LDS; input broadcast via b128 LDS read.
__global__ __launch_bounds__(256, 2) void k_layer(
        const float* __restrict__ agg, const float* __restrict__ ee,
        const float* __restrict__ cur, const float* __restrict__ deg,
        const float* __restrict__ Wm, const float* __restrict__ Wu,
        float* __restrict__ out) {
    __shared__ float SWm[128 * 64];
    __shared__ float SWu[128 * 64];
    __shared__ __align__(16) float SIN[4][128][4];   // [wave][k][node]
    int t = threadIdx.x;
    for (int i = t; i < 8192; i += 256) { SWm[i] = Wm[i]; SWu[i] = Wu[i]; }
    __syncthreads();
    int wv = t >> 6, lane = t & 63;
    int wg = blockIdx.x * 4 + wv, nw = gridDim.x * 4;
    for (int base = wg * 4; base < N_NODES; base += nw * 4) {
        int nn[4]; float di[4];
#pragma unroll
        for (int m = 0; m < 4; m++) {
            int n = base + m; if (n >= N_NODES) n = base;
            nn[m] = n;
            di[m] = 1.0f / deg[n];
        }
        // stage msg inputs: k<64 -> deg_inv*agg ; k>=64 -> ee
#pragma unroll
        for (int m = 0; m < 4; m++) {
            SIN[wv][lane][m]      = agg[nn[m] * 64 + lane] * di[m];
            SIN[wv][64 + lane][m] = ee[nn[m] * 64 + lane];
        }
        float a0 = 0, a1 = 0, a2 = 0, a3 = 0;
#pragma unroll 16
        for (int k = 0; k < 128; k++) {
            float4 v = *(const float4*)&SIN[wv][k][0];   // broadcast
            float w = SWm[k * 64 + lane];                // 2-way alias: free
            a0 = fmaf(v.x, w, a0); a1 = fmaf(v.y, w, a1);
            a2 = fmaf(v.z, w, a2); a3 = fmaf(v.w, w, a3);
        }
        // restage for upd: k<64 -> cur ; k>=64 -> msg (wave-synchronous reuse of SIN)
#pragma unroll
        for (int m = 0; m < 4; m++) SIN[wv][lane][m] = cur[nn[m] * 64 + lane];
        SIN[wv][64 + lane][0] = fmaxf(a0, 0.f);
        SIN[wv][64 + lane][1] = fmaxf(a1, 0.f);
        SIN[wv][64 + lane][2] = fmaxf(a2, 0.f);
        SIN[wv][64 + lane][3] = fmaxf(a3, 0.f);
        a0 = a1 = a2 = a3 = 0;
#pragma unroll 16
        for (int k = 0; k < 128; k++) {
            float4 v = *(const float4*)&SIN[wv][k][0];
            float w = SWu[k * 64 + lane];
            a0 = fmaf(v.x, w, a0); a1 = fmaf(v.y, w, a1);
            a2 = fmaf(v.z, w, a2); a3 = fmaf(v.w, w, a3);
        }
        float r[4] = { a0, a1, a2, a3 };
#pragma unroll
        for (int m = 0; m < 4; m++) {
            int n = base + m;
            if (n < N_NODES) out[n * 64 + lane] = fmaxf(r[m], 0.f);
        }
    }
}

// per-graph mean of cur (graphs are contiguous 1000-node ranges; batch sorted)
__global__ void k_means(const float* __restrict__ cur, float* __restrict__ means) {
    int g = blockIdx.x;
    int t = threadIdx.x, f = t & 63, q = t >> 6;
    float acc = 0.f;
    for (int n = g * NPG + q; n < (g + 1) * NPG; n += 4) acc += cur[n * 64 + f];
    __shared__ float red[4][64];
    red[q][f] = acc;
    __syncthreads();
    if (q == 0)
        means[g * 64 + f] = (red[0][f] + red[1][f] + red[2][f] + red[3][f]) * (1.0f / NPG);
}

// out[n] = b + sum_f relu((means[batch[n]] @ Wp)[f]) * Wr[f] + sum_f relu(cur[n][f]) * Wr[64+f]
__global__ __launch_bounds__(256) void k_readout(
        const float* __restrict__ cur, const float* __restrict__ means,
        const int* __restrict__ batch, const float* __restrict__ Wp,
        const float* __restrict__ Wr, const float* __restrict__ br,
        float* __restrict__ out) {
    __shared__ float W[64 * 64];
    __shared__ float R[128];
    __shared__ float GP[4][64];
    int t = threadIdx.x;
    for (int i = t; i < 4096; i += 256) W[i] = Wp[i];
    if (t < 128) R[t] = Wr[t];
    __syncthreads();
    int wv = t >> 6, lane = t & 63;
    float b = br[0];
    int wg = blockIdx.x * 4 + wv, nw = gridDim.x * 4;
    for (int node = wg; node < N_NODES; node += nw) {
        int g = batch[node];
        GP[wv][lane] = means[g * 64 + lane];
        float acc = 0.f;
#pragma unroll 16
        for (int k = 0; k < 64; k++) acc = fmaf(GP[wv][k], W[k * 64 + lane], acc);
        float v = fmaxf(acc, 0.f) * R[lane]
                + fmaxf(cur[node * 64 + lane], 0.f) * R[64 + lane];
        for (int off = 32; off; off >>= 1) v += __shfl_xor(v, off, 64);
        if (lane == 0) out[node] = v + b;
    }
}

// ---------------------------------------------------------------------------
extern "C" void kernel_launch(void* const* d_in, const int* in_sizes, int n_in,
                              void* d_out, int out_size, void* d_ws, size_t ws_size,
                              hipStream_t stream) {
    const float* x    = (const float*)d_in[0];
    const float* Wi   = (const float*)d_in[1];
    const float* We1  = (const float*)d_in[2];
    const float* We2  = (const float*)d_in[3];
    const float* Wm   = (const float*)d_in[4];   // [3,128,64]
    const float* Wu   = (const float*)d_in[5];   // [3,128,64]
    const float* Wp   = (const float*)d_in[6];
    const float* Wr   = (const float*)d_in[7];
    const float* br   = (const float*)d_in[8];
    const int*   ei   = (const int*)d_in[9];     // [2,E]
    const int*   batch= (const int*)d_in[10];
    const int* row = ei;
    const int* col = ei + N_EDGES;
    float* out = (float*)d_out;

    // workspace carve-up (256B aligned)
    char* w = (char*)d_ws;
    size_t off = 0;
    auto carve = [&](size_t bytes) -> float* {
        float* p = (float*)(w + off);
        off += (bytes + 255) & ~(size_t)255;
        return p;
    };
    float* deg   = carve((size_t)N_NODES * 4);
    float* cur0  = carve((size_t)N_NODES * 64 * 4);
    float* cur1  = carve((size_t)N_NODES * 64 * 4);
    float* agg   = carve((size_t)N_NODES * 64 * 4);
    float* ee    = carve((size_t)N_NODES * 64 * 4);
    float* means = carve((size_t)NG * 64 * 4);
    float* dmax  = carve(256);

    hipMemsetAsync(deg,  0, (size_t)N_NODES * 4, stream);
    hipMemsetAsync(agg,  0, (size_t)N_NODES * 64 * 4, stream);
    hipMemsetAsync(dmax, 0, 4, stream);

    k_deg   <<<(N_EDGES + 255) / 256, 256, 0, stream>>>(col, deg);
    k_degmax<<<(N_NODES + 255) / 256, 256, 0, stream>>>(deg, dmax);
    k_init  <<<(N_NODES * 64) / 256, 256, 0, stream>>>(x, Wi, We1, cur0, cur1); // cur1 = h

    k_scatter<<<(N_EDGES * 16) / 256, 256, 0, stream>>>(cur1, agg, row, col);
    k_edge_emb<<<1024, 256, 0, stream>>>(agg, deg, dmax, We2, ee);

    float* src = cur0;
    float* dst = cur1;
    for (int i = 0; i < 3; i++) {
        hipMemsetAsync(agg, 0, (size_t)N_NODES * 64 * 4, stream);
        k_scatter<<<(N_EDGES * 16) / 256, 256, 0, stream>>>(src, agg, row, col);
        k_layer<<<512, 256, 0, stream>>>(agg, ee, src, deg,
                                         Wm + (size_t)i * 128 * 64,
                                         Wu + (size_t)i * 128 * 64, dst);
        float* tmp = src; src = dst; dst = tmp;
    }

    k_means  <<<NG, 256, 0, stream>>>(src, means);
    k_readout<<<1024, 256, 0, stream>>>(src, means, batch, Wp, Wr, br, out);
}

// Round 2
// 764.612 us; speedup vs baseline: 4.0936x; 4.0936x over previous
//
#include <hip/hip_runtime.h>
#include <hip/hip_bf16.h>

#define N_NODES 50000
#define N_EDGES 800000
#define NF      64
#define NG      50
#define NPG     (N_NODES / NG)   // 1000 nodes per graph

// ---------------------------------------------------------------------------
// degree histogram (int): deg[col[e]] += 1
__global__ void k_deg(const int* __restrict__ col, int* __restrict__ deg) {
    int e = blockIdx.x * 256 + threadIdx.x;
    if (e < N_EDGES) atomicAdd(&deg[col[e]], 1);
}

// max(deg) -> dmax (int)
__global__ void k_degmax(const int* __restrict__ deg, int* __restrict__ dmax) {
    int i = blockIdx.x * 256 + threadIdx.x;
    int m = (i < N_NODES) ? deg[i] : 0;
    for (int off = 32; off; off >>= 1) m = max(m, __shfl_xor(m, off, 64));
    if ((threadIdx.x & 63) == 0) atomicMax(dmax, m);
}

// single-block exclusive scan of deg -> rowptr[0..N] ; also seeds cursor = rowptr
__global__ __launch_bounds__(1024) void k_scan(const int* __restrict__ deg,
                                               int* __restrict__ rowptr,
                                               int* __restrict__ cursor) {
    __shared__ int partial[1024];
    int t = threadIdx.x;
    const int CH = (N_NODES + 1023) / 1024;   // 49
    int base = t * CH;
    int s = 0;
    for (int i = 0; i < CH; i++) { int idx = base + i; if (idx < N_NODES) s += deg[idx]; }
    partial[t] = s;
    __syncthreads();
    for (int off = 1; off < 1024; off <<= 1) {
        int v = (t >= off) ? partial[t - off] : 0;
        __syncthreads();
        partial[t] += v;
        __syncthreads();
    }
    int ex = (t == 0) ? 0 : partial[t - 1];
    for (int i = 0; i < CH; i++) {
        int idx = base + i;
        if (idx < N_NODES) { rowptr[idx] = ex; cursor[idx] = ex; ex += deg[idx]; }
    }
    if (t == 1023) rowptr[N_NODES] = ex;
}

// csr[slot] = row[e], slot allocated per destination node
__global__ void k_fill(const int* __restrict__ row, const int* __restrict__ col,
                       int* __restrict__ cursor, int* __restrict__ csr) {
    int e = blockIdx.x * 256 + threadIdx.x;
    if (e >= N_EDGES) return;
    int pos = atomicAdd(&cursor[col[e]], 1);
    csr[pos] = row[e];
}

// cur = relu(x @ W_init) [N,64];  h = relu(x @ W_e1) [N,63] stored padded [N,64] (lane63 = 0)
__global__ void k_init(const float* __restrict__ x, const float* __restrict__ Wi,
                       const float* __restrict__ We1,
                       float* __restrict__ cur, float* __restrict__ h) {
    int idx = blockIdx.x * 256 + threadIdx.x;
    int node = idx >> 6, f = idx & 63;
    if (node >= N_NODES) return;
    float4 xv = ((const float4*)x)[node];
    float c = xv.x * Wi[f] + xv.y * Wi[64 + f] + xv.z * Wi[128 + f] + xv.w * Wi[192 + f];
    cur[idx] = fmaxf(c, 0.f);
    float hv = 0.f;
    if (f < 63) {
        hv = xv.x * We1[f] + xv.y * We1[63 + f] + xv.z * We1[126 + f] + xv.w * We1[189 + f];
        hv = fmaxf(hv, 0.f);
    }
    h[idx] = hv;
}

// agg[n] = (1/deg[n]) * sum_{e: col[e]==n} src[row[e]]   -- one wave per node, no atomics
__global__ void k_gather(const float* __restrict__ src, float* __restrict__ agg,
                         const int* __restrict__ rowptr, const int* __restrict__ csr) {
    int wid = (blockIdx.x * 256 + threadIdx.x) >> 6;
    int lane = threadIdx.x & 63;
    if (wid >= N_NODES) return;
    int beg = rowptr[wid], end = rowptr[wid + 1];
    float acc = 0.f;
    int j = beg;
    for (; j + 1 < end; j += 2) {                 // 2-deep for load ILP
        int r0 = csr[j], r1 = csr[j + 1];
        float v0 = src[r0 * 64 + lane];
        float v1 = src[r1 * 64 + lane];
        acc += v0; acc += v1;
    }
    if (j < end) acc += src[csr[j] * 64 + lane];
    agg[wid * 64 + lane] = acc * (1.0f / (float)(end - beg));   // deg > 0 always
}

// edge_emb = relu( [agg(63, pre-normalized) | deg/degmax(1)] @ W_e2 )
__global__ __launch_bounds__(256) void k_edge_emb(
        const float* __restrict__ agg, const int* __restrict__ deg,
        const int* __restrict__ dmax, const float* __restrict__ We2,
        float* __restrict__ ee) {
    __shared__ float W[64 * 64];
    __shared__ float Y[4][64];
    int t = threadIdx.x;
    for (int i = t; i < 4096; i += 256) W[i] = We2[i];
    __syncthreads();
    int wv = t >> 6, lane = t & 63;
    float idm = 1.0f / (float)dmax[0];
    int wg = blockIdx.x * 4 + wv, nw = gridDim.x * 4;
    for (int node = wg; node < N_NODES; node += nw) {
        float y = (lane < 63) ? agg[node * 64 + lane] : (float)deg[node] * idm;
        Y[wv][lane] = y;                       // wave-synchronous: no barrier needed
        float acc = 0.f;
#pragma unroll 16
        for (int k = 0; k < 64; k++) acc = fmaf(Y[wv][k], W[k * 64 + lane], acc);
        ee[node * 64 + lane] = fmaxf(acc, 0.f);
    }
}

// one MPNN layer: msg = relu([agg | ee] @ Wm); out = relu([cur | msg] @ Wu)
// wave processes 4 nodes; weights in LDS; input broadcast via b128 LDS read.
__global__ __launch_bounds__(256, 2) void k_layer(
        const float* __restrict__ agg, const float* __restrict__ ee,
        const float* __restrict__ cur,
        const float* __restrict__ Wm, const float* __restrict__ Wu,
        float* __restrict__ out) {
    __shared__ float SWm[128 * 64];
    __shared__ float SWu[128 * 64];
    __shared__ __align__(16) float SIN[4][128][4];   // [wave][k][node]
    int t = threadIdx.x;
    for (int i = t; i < 8192; i += 256) { SWm[i] = Wm[i]; SWu[i] = Wu[i]; }
    __syncthreads();
    int wv = t >> 6, lane = t & 63;
    int wg = blockIdx.x * 4 + wv, nw = gridDim.x * 4;
    for (int base = wg * 4; base < N_NODES; base += nw * 4) {
        int nn[4];
#pragma unroll
        for (int m = 0; m < 4; m++) {
            int n = base + m; if (n >= N_NODES) n = base;
            nn[m] = n;
        }
        // stage msg inputs: k<64 -> agg (pre-normalized) ; k>=64 -> ee
#pragma unroll
        for (int m = 0; m < 4; m++) {
            SIN[wv][lane][m]      = agg[nn[m] * 64 + lane];
            SIN[wv][64 + lane][m] = ee[nn[m] * 64 + lane];
        }
        float a0 = 0, a1 = 0, a2 = 0, a3 = 0;
#pragma unroll 16
        for (int k = 0; k < 128; k++) {
            float4 v = *(const float4*)&SIN[wv][k][0];   // broadcast
            float w = SWm[k * 64 + lane];                // 2-way alias: free
            a0 = fmaf(v.x, w, a0); a1 = fmaf(v.y, w, a1);
            a2 = fmaf(v.z, w, a2); a3 = fmaf(v.w, w, a3);
        }
        // restage for upd: k<64 -> cur ; k>=64 -> msg (wave-synchronous reuse of SIN)
#pragma unroll
        for (int m = 0; m < 4; m++) SIN[wv][lane][m] = cur[nn[m] * 64 + lane];
        SIN[wv][64 + lane][0] = fmaxf(a0, 0.f);
        SIN[wv][64 + lane][1] = fmaxf(a1, 0.f);
        SIN[wv][64 + lane][2] = fmaxf(a2, 0.f);
        SIN[wv][64 + lane][3] = fmaxf(a3, 0.f);
        a0 = a1 = a2 = a3 = 0;
#pragma unroll 16
        for (int k = 0; k < 128; k++) {
            float4 v = *(const float4*)&SIN[wv][k][0];
            float w = SWu[k * 64 + lane];
            a0 = fmaf(v.x, w, a0); a1 = fmaf(v.y, w, a1);
            a2 = fmaf(v.z, w, a2); a3 = fmaf(v.w, w, a3);
        }
        float r[4] = { a0, a1, a2, a3 };
#pragma unroll
        for (int m = 0; m < 4; m++) {
            int n = base + m;
            if (n < N_NODES) out[n * 64 + lane] = fmaxf(r[m], 0.f);
        }
    }
}

// per-graph mean of cur (graphs are contiguous 1000-node ranges; batch sorted)
__global__ void k_means(const float* __restrict__ cur, float* __restrict__ means) {
    int g = blockIdx.x;
    int t = threadIdx.x, f = t & 63, q = t >> 6;
    float acc = 0.f;
    for (int n = g * NPG + q; n < (g + 1) * NPG; n += 4) acc += cur[n * 64 + f];
    __shared__ float red[4][64];
    red[q][f] = acc;
    __syncthreads();
    if (q == 0)
        means[g * 64 + f] = (red[0][f] + red[1][f] + red[2][f] + red[3][f]) * (1.0f / NPG);
}

// out[n] = b + sum_f relu((means[batch[n]] @ Wp)[f]) * Wr[f] + sum_f relu(cur[n][f]) * Wr[64+f]
__global__ __launch_bounds__(256) void k_readout(
        const float* __restrict__ cur, const float* __restrict__ means,
        const int* __restrict__ batch, const float* __restrict__ Wp,
        const float* __restrict__ Wr, const float* __restrict__ br,
        float* __restrict__ out) {
    __shared__ float W[64 * 64];
    __shared__ float R[128];
    __shared__ float GP[4][64];
    int t = threadIdx.x;
    for (int i = t; i < 4096; i += 256) W[i] = Wp[i];
    if (t < 128) R[t] = Wr[t];
    __syncthreads();
    int wv = t >> 6, lane = t & 63;
    float b = br[0];
    int wg = blockIdx.x * 4 + wv, nw = gridDim.x * 4;
    for (int node = wg; node < N_NODES; node += nw) {
        int g = batch[node];
        GP[wv][lane] = means[g * 64 + lane];
        float acc = 0.f;
#pragma unroll 16
        for (int k = 0; k < 64; k++) acc = fmaf(GP[wv][k], W[k * 64 + lane], acc);
        float v = fmaxf(acc, 0.f) * R[lane]
                + fmaxf(cur[node * 64 + lane], 0.f) * R[64 + lane];
        for (int off = 32; off; off >>= 1) v += __shfl_xor(v, off, 64);
        if (lane == 0) out[node] = v + b;
    }
}

// ---------------------------------------------------------------------------
extern "C" void kernel_launch(void* const* d_in, const int* in_sizes, int n_in,
                              void* d_out, int out_size, void* d_ws, size_t ws_size,
                              hipStream_t stream) {
    const float* x    = (const float*)d_in[0];
    const float* Wi   = (const float*)d_in[1];
    const float* We1  = (const float*)d_in[2];
    const float* We2  = (const float*)d_in[3];
    const float* Wm   = (const float*)d_in[4];   // [3,128,64]
    const float* Wu   = (const float*)d_in[5];   // [3,128,64]
    const float* Wp   = (const float*)d_in[6];
    const float* Wr   = (const float*)d_in[7];
    const float* br   = (const float*)d_in[8];
    const int*   ei   = (const int*)d_in[9];     // [2,E]
    const int*   batch= (const int*)d_in[10];
    const int* row = ei;
    const int* col = ei + N_EDGES;
    float* out = (float*)d_out;

    // workspace carve-up (256B aligned)
    char* w = (char*)d_ws;
    size_t off = 0;
    auto carve = [&](size_t bytes) -> void* {
        void* p = (void*)(w + off);
        off += (bytes + 255) & ~(size_t)255;
        return p;
    };
    int*   deg    = (int*)carve((size_t)N_NODES * 4);
    int*   rowptr = (int*)carve((size_t)(N_NODES + 1) * 4);
    int*   cursor = (int*)carve((size_t)N_NODES * 4);
    int*   csr    = (int*)carve((size_t)N_EDGES * 4);
    float* cur0   = (float*)carve((size_t)N_NODES * 64 * 4);
    float* cur1   = (float*)carve((size_t)N_NODES * 64 * 4);
    float* agg    = (float*)carve((size_t)N_NODES * 64 * 4);
    float* ee     = (float*)carve((size_t)N_NODES * 64 * 4);
    float* means  = (float*)carve((size_t)NG * 64 * 4);
    int*   dmax   = (int*)carve(256);

    hipMemsetAsync(deg,  0, (size_t)N_NODES * 4, stream);
    hipMemsetAsync(dmax, 0, 4, stream);

    // CSR build (by destination)
    k_deg   <<<(N_EDGES + 255) / 256, 256, 0, stream>>>(col, deg);
    k_degmax<<<(N_NODES + 255) / 256, 256, 0, stream>>>(deg, dmax);
    k_scan  <<<1, 1024, 0, stream>>>(deg, rowptr, cursor);
    k_fill  <<<(N_EDGES + 255) / 256, 256, 0, stream>>>(row, col, cursor, csr);

    k_init  <<<(N_NODES * 64) / 256, 256, 0, stream>>>(x, Wi, We1, cur0, cur1); // cur1 = h

    k_gather<<<(N_NODES * 64 + 255) / 256, 256, 0, stream>>>(cur1, agg, rowptr, csr);
    k_edge_emb<<<1024, 256, 0, stream>>>(agg, deg, dmax, We2, ee);

    float* src = cur0;
    float* dst = cur1;
    for (int i = 0; i < 3; i++) {
        k_gather<<<(N_NODES * 64 + 255) / 256, 256, 0, stream>>>(src, agg, rowptr, csr);
        k_layer<<<512, 256, 0, stream>>>(agg, ee, src,
                                         Wm + (size_t)i * 128 * 64,
                                         Wu + (size_t)i * 128 * 64, dst);
        float* tmp = src; src = dst; dst = tmp;
    }

    k_means  <<<NG, 256, 0, stream>>>(src, means);
    k_readout<<<1024, 256, 0, stream>>>(src, means, batch, Wp, Wr, br, out);
}

// Round 3
// 578.195 us; speedup vs baseline: 5.4134x; 1.3224x over previous
//
#include <hip/hip_runtime.h>
#include <hip/hip_bf16.h>

#define N_NODES 50000
#define N_EDGES 800000
#define NF      64
#define NG      50
#define NPG     (N_NODES / NG)   // 1000 nodes per graph
#define SCAN_NBLK ((N_NODES + 255) / 256)   // 196

// ---------------------------------------------------------------------------
// degree histogram (int): deg[col[e]] += 1
__global__ void k_deg(const int* __restrict__ col, int* __restrict__ deg) {
    int e = blockIdx.x * 256 + threadIdx.x;
    if (e < N_EDGES) atomicAdd(&deg[col[e]], 1);
}

// max(deg) -> dmax (int)
__global__ void k_degmax(const int* __restrict__ deg, int* __restrict__ dmax) {
    int i = blockIdx.x * 256 + threadIdx.x;
    int m = (i < N_NODES) ? deg[i] : 0;
    for (int off = 32; off; off >>= 1) m = max(m, __shfl_xor(m, off, 64));
    if ((threadIdx.x & 63) == 0) atomicMax(dmax, m);
}

// ---- hierarchical scan: blocksum -> scan partials -> rescan with offset ----
__global__ void k_blocksum(const int* __restrict__ deg, int* __restrict__ partials) {
    int i = blockIdx.x * 256 + threadIdx.x;
    int v = (i < N_NODES) ? deg[i] : 0;
    for (int off = 32; off; off >>= 1) v += __shfl_xor(v, off, 64);
    __shared__ int s[4];
    if ((threadIdx.x & 63) == 0) s[threadIdx.x >> 6] = v;
    __syncthreads();
    if (threadIdx.x == 0) partials[blockIdx.x] = s[0] + s[1] + s[2] + s[3];
}

__global__ void k_scanpartials(int* __restrict__ partials, int* __restrict__ rowptr) {
    __shared__ int s[256];
    int t = threadIdx.x;
    int v = (t < SCAN_NBLK) ? partials[t] : 0;
    s[t] = v;
    __syncthreads();
    for (int off = 1; off < 256; off <<= 1) {
        int u = (t >= off) ? s[t - off] : 0;
        __syncthreads();
        s[t] += u;
        __syncthreads();
    }
    if (t < SCAN_NBLK) partials[t] = s[t] - v;   // exclusive block offsets
    if (t == 0) rowptr[N_NODES] = N_EDGES;       // total is a constant
}

__global__ void k_scanfinal(const int* __restrict__ deg, const int* __restrict__ partials,
                            int* __restrict__ rowptr, int* __restrict__ cursor) {
    int t = threadIdx.x;
    int i = blockIdx.x * 256 + t;
    int v = (i < N_NODES) ? deg[i] : 0;
    __shared__ int s[256];
    s[t] = v;
    __syncthreads();
    for (int off = 1; off < 256; off <<= 1) {
        int u = (t >= off) ? s[t - off] : 0;
        __syncthreads();
        s[t] += u;
        __syncthreads();
    }
    int ex = s[t] - v + partials[blockIdx.x];
    if (i < N_NODES) { rowptr[i] = ex; cursor[i] = ex; }
}

// csr[slot] = row[e], slot allocated per destination node
__global__ void k_fill(const int* __restrict__ row, const int* __restrict__ col,
                       int* __restrict__ cursor, int* __restrict__ csr) {
    int e = blockIdx.x * 256 + threadIdx.x;
    if (e >= N_EDGES) return;
    int pos = atomicAdd(&cursor[col[e]], 1);
    csr[pos] = row[e];
}

// cur = relu(x @ W_init) [N,64];  h = relu(x @ W_e1) [N,63] stored padded [N,64] (lane63 = 0)
__global__ void k_init(const float* __restrict__ x, const float* __restrict__ Wi,
                       const float* __restrict__ We1,
                       float* __restrict__ cur, float* __restrict__ h) {
    int idx = blockIdx.x * 256 + threadIdx.x;
    int node = idx >> 6, f = idx & 63;
    if (node >= N_NODES) return;
    float4 xv = ((const float4*)x)[node];
    float c = xv.x * Wi[f] + xv.y * Wi[64 + f] + xv.z * Wi[128 + f] + xv.w * Wi[192 + f];
    cur[idx] = fmaxf(c, 0.f);
    float hv = 0.f;
    if (f < 63) {
        hv = xv.x * We1[f] + xv.y * We1[63 + f] + xv.z * We1[126 + f] + xv.w * We1[189 + f];
        hv = fmaxf(hv, 0.f);
    }
    h[idx] = hv;
}

// agg[n] = (1/deg[n]) * sum_{e: col[e]==n} src[row[e]]
// one wave per node; quarter-wave (16 lanes) per edge slot, float4 per lane
__global__ void k_gather(const float* __restrict__ src, float* __restrict__ agg,
                         const int* __restrict__ rowptr, const int* __restrict__ csr) {
    int wid = (blockIdx.x * 256 + threadIdx.x) >> 6;
    if (wid >= N_NODES) return;
    int lane = threadIdx.x & 63;
    int grp = lane >> 4;           // edge slot 0..3
    int fl  = (lane & 15) << 2;    // feature quad base
    int beg = rowptr[wid], end = rowptr[wid + 1];
    float4 acc = { 0.f, 0.f, 0.f, 0.f };
    for (int j = beg + grp; j < end; j += 4) {
        int r = csr[j];
        float4 v = *(const float4*)(src + r * 64 + fl);
        acc.x += v.x; acc.y += v.y; acc.z += v.z; acc.w += v.w;
    }
    // lanes L, L+16, L+32, L+48 hold the same feature quad -> butterfly over groups
#pragma unroll
    for (int off = 16; off <= 32; off <<= 1) {
        acc.x += __shfl_xor(acc.x, off, 64);
        acc.y += __shfl_xor(acc.y, off, 64);
        acc.z += __shfl_xor(acc.z, off, 64);
        acc.w += __shfl_xor(acc.w, off, 64);
    }
    if (lane < 16) {
        float inv = 1.0f / (float)(end - beg);   // deg > 0 always
        float4 o = { acc.x * inv, acc.y * inv, acc.z * inv, acc.w * inv };
        *(float4*)(agg + wid * 64 + fl) = o;
    }
}

// edge_emb = relu( [agg(63, pre-normalized) | deg/degmax(1)] @ W_e2 )
__global__ __launch_bounds__(256) void k_edge_emb(
        const float* __restrict__ agg, const int* __restrict__ deg,
        const int* __restrict__ dmax, const float* __restrict__ We2,
        float* __restrict__ ee) {
    __shared__ float W[64 * 64];
    __shared__ float Y[4][64];
    int t = threadIdx.x;
    for (int i = t; i < 4096; i += 256) W[i] = We2[i];
    __syncthreads();
    int wv = t >> 6, lane = t & 63;
    float idm = 1.0f / (float)dmax[0];
    int wg = blockIdx.x * 4 + wv, nw = gridDim.x * 4;
    for (int node = wg; node < N_NODES; node += nw) {
        float y = (lane < 63) ? agg[node * 64 + lane] : (float)deg[node] * idm;
        Y[wv][lane] = y;                       // wave-synchronous: no barrier needed
        float acc = 0.f;
#pragma unroll 16
        for (int k = 0; k < 64; k++) acc = fmaf(Y[wv][k], W[k * 64 + lane], acc);
        ee[node * 64 + lane] = fmaxf(acc, 0.f);
    }
}

// one MPNN layer: msg = relu([agg | ee] @ Wm); out = relu([cur | msg] @ Wu)
__global__ __launch_bounds__(256, 2) void k_layer(
        const float* __restrict__ agg, const float* __restrict__ ee,
        const float* __restrict__ cur,
        const float* __restrict__ Wm, const float* __restrict__ Wu,
        float* __restrict__ out) {
    __shared__ float SWm[128 * 64];
    __shared__ float SWu[128 * 64];
    __shared__ __align__(16) float SIN[4][128][4];   // [wave][k][node]
    int t = threadIdx.x;
    for (int i = t; i < 8192; i += 256) { SWm[i] = Wm[i]; SWu[i] = Wu[i]; }
    __syncthreads();
    int wv = t >> 6, lane = t & 63;
    int wg = blockIdx.x * 4 + wv, nw = gridDim.x * 4;
    for (int base = wg * 4; base < N_NODES; base += nw * 4) {
        int nn[4];
#pragma unroll
        for (int m = 0; m < 4; m++) {
            int n = base + m; if (n >= N_NODES) n = base;
            nn[m] = n;
        }
#pragma unroll
        for (int m = 0; m < 4; m++) {
            SIN[wv][lane][m]      = agg[nn[m] * 64 + lane];
            SIN[wv][64 + lane][m] = ee[nn[m] * 64 + lane];
        }
        float a0 = 0, a1 = 0, a2 = 0, a3 = 0;
#pragma unroll 16
        for (int k = 0; k < 128; k++) {
            float4 v = *(const float4*)&SIN[wv][k][0];   // broadcast
            float w = SWm[k * 64 + lane];                // 2-way alias: free
            a0 = fmaf(v.x, w, a0); a1 = fmaf(v.y, w, a1);
            a2 = fmaf(v.z, w, a2); a3 = fmaf(v.w, w, a3);
        }
#pragma unroll
        for (int m = 0; m < 4; m++) SIN[wv][lane][m] = cur[nn[m] * 64 + lane];
        SIN[wv][64 + lane][0] = fmaxf(a0, 0.f);
        SIN[wv][64 + lane][1] = fmaxf(a1, 0.f);
        SIN[wv][64 + lane][2] = fmaxf(a2, 0.f);
        SIN[wv][64 + lane][3] = fmaxf(a3, 0.f);
        a0 = a1 = a2 = a3 = 0;
#pragma unroll 16
        for (int k = 0; k < 128; k++) {
            float4 v = *(const float4*)&SIN[wv][k][0];
            float w = SWu[k * 64 + lane];
            a0 = fmaf(v.x, w, a0); a1 = fmaf(v.y, w, a1);
            a2 = fmaf(v.z, w, a2); a3 = fmaf(v.w, w, a3);
        }
        float r[4] = { a0, a1, a2, a3 };
#pragma unroll
        for (int m = 0; m < 4; m++) {
            int n = base + m;
            if (n < N_NODES) out[n * 64 + lane] = fmaxf(r[m], 0.f);
        }
    }
}

// per-graph mean of cur (graphs are contiguous 1000-node ranges; batch sorted)
__global__ void k_means(const float* __restrict__ cur, float* __restrict__ means) {
    int g = blockIdx.x;
    int t = threadIdx.x, f = t & 63, q = t >> 6;
    float acc = 0.f;
    for (int n = g * NPG + q; n < (g + 1) * NPG; n += 4) acc += cur[n * 64 + f];
    __shared__ float red[4][64];
    red[q][f] = acc;
    __syncthreads();
    if (q == 0)
        means[g * 64 + f] = (red[0][f] + red[1][f] + red[2][f] + red[3][f]) * (1.0f / NPG);
}

// out[n] = b + sum_f relu((means[batch[n]] @ Wp)[f]) * Wr[f] + sum_f relu(cur[n][f]) * Wr[64+f]
__global__ __launch_bounds__(256) void k_readout(
        const float* __restrict__ cur, const float* __restrict__ means,
        const int* __restrict__ batch, const float* __restrict__ Wp,
        const float* __restrict__ Wr, const float* __restrict__ br,
        float* __restrict__ out) {
    __shared__ float W[64 * 64];
    __shared__ float R[128];
    __shared__ float GP[4][64];
    int t = threadIdx.x;
    for (int i = t; i < 4096; i += 256) W[i] = Wp[i];
    if (t < 128) R[t] = Wr[t];
    __syncthreads();
    int wv = t >> 6, lane = t & 63;
    float b = br[0];
    int wg = blockIdx.x * 4 + wv, nw = gridDim.x * 4;
    for (int node = wg; node < N_NODES; node += nw) {
        int g = batch[node];
        GP[wv][lane] = means[g * 64 + lane];
        float acc = 0.f;
#pragma unroll 16
        for (int k = 0; k < 64; k++) acc = fmaf(GP[wv][k], W[k * 64 + lane], acc);
        float v = fmaxf(acc, 0.f) * R[lane]
                + fmaxf(cur[node * 64 + lane], 0.f) * R[64 + lane];
        for (int off = 32; off; off >>= 1) v += __shfl_xor(v, off, 64);
        if (lane == 0) out[node] = v + b;
    }
}

// ---------------------------------------------------------------------------
extern "C" void kernel_launch(void* const* d_in, const int* in_sizes, int n_in,
                              void* d_out, int out_size, void* d_ws, size_t ws_size,
                              hipStream_t stream) {
    const float* x    = (const float*)d_in[0];
    const float* Wi   = (const float*)d_in[1];
    const float* We1  = (const float*)d_in[2];
    const float* We2  = (const float*)d_in[3];
    const float* Wm   = (const float*)d_in[4];   // [3,128,64]
    const float* Wu   = (const float*)d_in[5];   // [3,128,64]
    const float* Wp   = (const float*)d_in[6];
    const float* Wr   = (const float*)d_in[7];
    const float* br   = (const float*)d_in[8];
    const int*   ei   = (const int*)d_in[9];     // [2,E]
    const int*   batch= (const int*)d_in[10];
    const int* row = ei;
    const int* col = ei + N_EDGES;
    float* out = (float*)d_out;

    // workspace carve-up (256B aligned)
    char* w = (char*)d_ws;
    size_t off = 0;
    auto carve = [&](size_t bytes) -> void* {
        void* p = (void*)(w + off);
        off += (bytes + 255) & ~(size_t)255;
        return p;
    };
    int*   deg      = (int*)carve((size_t)N_NODES * 4);
    int*   rowptr   = (int*)carve((size_t)(N_NODES + 1) * 4);
    int*   cursor   = (int*)carve((size_t)N_NODES * 4);
    int*   csr      = (int*)carve((size_t)N_EDGES * 4);
    int*   partials = (int*)carve((size_t)SCAN_NBLK * 4);
    float* cur0     = (float*)carve((size_t)N_NODES * 64 * 4);
    float* cur1     = (float*)carve((size_t)N_NODES * 64 * 4);
    float* agg      = (float*)carve((size_t)N_NODES * 64 * 4);
    float* ee       = (float*)carve((size_t)N_NODES * 64 * 4);
    float* means    = (float*)carve((size_t)NG * 64 * 4);
    int*   dmax     = (int*)carve(256);

    hipMemsetAsync(deg,  0, (size_t)N_NODES * 4, stream);
    hipMemsetAsync(dmax, 0, 4, stream);

    // CSR build (by destination)
    k_deg         <<<(N_EDGES + 255) / 256, 256, 0, stream>>>(col, deg);
    k_degmax      <<<(N_NODES + 255) / 256, 256, 0, stream>>>(deg, dmax);
    k_blocksum    <<<SCAN_NBLK, 256, 0, stream>>>(deg, partials);
    k_scanpartials<<<1, 256, 0, stream>>>(partials, rowptr);
    k_scanfinal   <<<SCAN_NBLK, 256, 0, stream>>>(deg, partials, rowptr, cursor);
    k_fill        <<<(N_EDGES + 255) / 256, 256, 0, stream>>>(row, col, cursor, csr);

    k_init  <<<(N_NODES * 64) / 256, 256, 0, stream>>>(x, Wi, We1, cur0, cur1); // cur1 = h

    k_gather<<<(N_NODES * 64 + 255) / 256, 256, 0, stream>>>(cur1, agg, rowptr, csr);
    k_edge_emb<<<1024, 256, 0, stream>>>(agg, deg, dmax, We2, ee);

    float* src = cur0;
    float* dst = cur1;
    for (int i = 0; i < 3; i++) {
        k_gather<<<(N_NODES * 64 + 255) / 256, 256, 0, stream>>>(src, agg, rowptr, csr);
        k_layer<<<512, 256, 0, stream>>>(agg, ee, src,
                                         Wm + (size_t)i * 128 * 64,
                                         Wu + (size_t)i * 128 * 64, dst);
        float* tmp = src; src = dst; dst = tmp;
    }

    k_means  <<<NG, 256, 0, stream>>>(src, means);
    k_readout<<<1024, 256, 0, stream>>>(src, means, batch, Wp, Wr, br, out);
}

// Round 4
// 511.989 us; speedup vs baseline: 6.1135x; 1.1293x over previous
//
#include <hip/hip_runtime.h>
#include <hip/hip_bf16.h>

#define N_NODES 50000
#define N_EDGES 800000
#define NF      64
#define NG      50
#define NPG     (N_NODES / NG)   // 1000 nodes per graph
#define SCAN_NBLK ((N_NODES + 255) / 256)   // 196
#define MCHUNK  20               // blocks per graph for means
#define MROWS   (NPG / MCHUNK)   // 50 nodes per means block

// ---------------------------------------------------------------------------
// degree histogram (int): deg[col[e]] += 1
__global__ void k_deg(const int* __restrict__ col, int* __restrict__ deg) {
    int e = blockIdx.x * 256 + threadIdx.x;
    if (e < N_EDGES) atomicAdd(&deg[col[e]], 1);
}

// max(deg) -> dmax (int)
__global__ void k_degmax(const int* __restrict__ deg, int* __restrict__ dmax) {
    int i = blockIdx.x * 256 + threadIdx.x;
    int m = (i < N_NODES) ? deg[i] : 0;
    for (int off = 32; off; off >>= 1) m = max(m, __shfl_xor(m, off, 64));
    if ((threadIdx.x & 63) == 0) atomicMax(dmax, m);
}

// ---- hierarchical scan: blocksum -> scan partials -> rescan with offset ----
__global__ void k_blocksum(const int* __restrict__ deg, int* __restrict__ partials) {
    int i = blockIdx.x * 256 + threadIdx.x;
    int v = (i < N_NODES) ? deg[i] : 0;
    for (int off = 32; off; off >>= 1) v += __shfl_xor(v, off, 64);
    __shared__ int s[4];
    if ((threadIdx.x & 63) == 0) s[threadIdx.x >> 6] = v;
    __syncthreads();
    if (threadIdx.x == 0) partials[blockIdx.x] = s[0] + s[1] + s[2] + s[3];
}

__global__ void k_scanpartials(int* __restrict__ partials, int* __restrict__ rowptr) {
    __shared__ int s[256];
    int t = threadIdx.x;
    int v = (t < SCAN_NBLK) ? partials[t] : 0;
    s[t] = v;
    __syncthreads();
    for (int off = 1; off < 256; off <<= 1) {
        int u = (t >= off) ? s[t - off] : 0;
        __syncthreads();
        s[t] += u;
        __syncthreads();
    }
    if (t < SCAN_NBLK) partials[t] = s[t] - v;   // exclusive block offsets
    if (t == 0) rowptr[N_NODES] = N_EDGES;       // total is a constant
}

__global__ void k_scanfinal(const int* __restrict__ deg, const int* __restrict__ partials,
                            int* __restrict__ rowptr, int* __restrict__ cursor) {
    int t = threadIdx.x;
    int i = blockIdx.x * 256 + t;
    int v = (i < N_NODES) ? deg[i] : 0;
    __shared__ int s[256];
    s[t] = v;
    __syncthreads();
    for (int off = 1; off < 256; off <<= 1) {
        int u = (t >= off) ? s[t - off] : 0;
        __syncthreads();
        s[t] += u;
        __syncthreads();
    }
    int ex = s[t] - v + partials[blockIdx.x];
    if (i < N_NODES) { rowptr[i] = ex; cursor[i] = ex; }
}

// csr[slot] = row[e], slot allocated per destination node
__global__ void k_fill(const int* __restrict__ row, const int* __restrict__ col,
                       int* __restrict__ cursor, int* __restrict__ csr) {
    int e = blockIdx.x * 256 + threadIdx.x;
    if (e >= N_EDGES) return;
    int pos = atomicAdd(&cursor[col[e]], 1);
    csr[pos] = row[e];
}

// cur = relu(x @ W_init) [N,64];  h = relu(x @ W_e1) [N,63] stored padded [N,64] (lane63 = 0)
__global__ void k_init(const float* __restrict__ x, const float* __restrict__ Wi,
                       const float* __restrict__ We1,
                       float* __restrict__ cur, float* __restrict__ h) {
    int idx = blockIdx.x * 256 + threadIdx.x;
    int node = idx >> 6, f = idx & 63;
    if (node >= N_NODES) return;
    float4 xv = ((const float4*)x)[node];
    float c = xv.x * Wi[f] + xv.y * Wi[64 + f] + xv.z * Wi[128 + f] + xv.w * Wi[192 + f];
    cur[idx] = fmaxf(c, 0.f);
    float hv = 0.f;
    if (f < 63) {
        hv = xv.x * We1[f] + xv.y * We1[63 + f] + xv.z * We1[126 + f] + xv.w * We1[189 + f];
        hv = fmaxf(hv, 0.f);
    }
    h[idx] = hv;
}

// agg[n] = (1/deg[n]) * sum_{e: col[e]==n} src[row[e]]
// one wave per node; quarter-wave (16 lanes) per edge slot, float4 per lane; 2x unroll
__global__ void k_gather(const float* __restrict__ src, float* __restrict__ agg,
                         const int* __restrict__ rowptr, const int* __restrict__ csr) {
    int wid = (blockIdx.x * 256 + threadIdx.x) >> 6;
    if (wid >= N_NODES) return;
    int lane = threadIdx.x & 63;
    int grp = lane >> 4;           // edge slot 0..3
    int fl  = (lane & 15) << 2;    // feature quad base
    int beg = rowptr[wid], end = rowptr[wid + 1];
    float4 acc = { 0.f, 0.f, 0.f, 0.f };
    int j = beg + grp;
    for (; j + 4 < end; j += 8) {             // two edges in flight per group
        int r0 = csr[j], r1 = csr[j + 4];
        float4 v0 = *(const float4*)(src + r0 * 64 + fl);
        float4 v1 = *(const float4*)(src + r1 * 64 + fl);
        acc.x += v0.x; acc.y += v0.y; acc.z += v0.z; acc.w += v0.w;
        acc.x += v1.x; acc.y += v1.y; acc.z += v1.z; acc.w += v1.w;
    }
    if (j < end) {
        int r = csr[j];
        float4 v = *(const float4*)(src + r * 64 + fl);
        acc.x += v.x; acc.y += v.y; acc.z += v.z; acc.w += v.w;
    }
    // lanes L, L+16, L+32, L+48 hold the same feature quad -> butterfly over groups
#pragma unroll
    for (int off = 16; off <= 32; off <<= 1) {
        acc.x += __shfl_xor(acc.x, off, 64);
        acc.y += __shfl_xor(acc.y, off, 64);
        acc.z += __shfl_xor(acc.z, off, 64);
        acc.w += __shfl_xor(acc.w, off, 64);
    }
    if (lane < 16) {
        float inv = 1.0f / (float)(end - beg);   // deg > 0 always
        float4 o = { acc.x * inv, acc.y * inv, acc.z * inv, acc.w * inv };
        *(float4*)(agg + wid * 64 + fl) = o;
    }
}

// edge_emb = relu( [agg(63, pre-normalized) | deg/degmax(1)] @ W_e2 )
__global__ __launch_bounds__(256) void k_edge_emb(
        const float* __restrict__ agg, const int* __restrict__ deg,
        const int* __restrict__ dmax, const float* __restrict__ We2,
        float* __restrict__ ee) {
    __shared__ float W[64 * 64];
    __shared__ float Y[4][64];
    int t = threadIdx.x;
    for (int i = t; i < 4096; i += 256) W[i] = We2[i];
    __syncthreads();
    int wv = t >> 6, lane = t & 63;
    float idm = 1.0f / (float)dmax[0];
    int wg = blockIdx.x * 4 + wv, nw = gridDim.x * 4;
    for (int node = wg; node < N_NODES; node += nw) {
        float y = (lane < 63) ? agg[node * 64 + lane] : (float)deg[node] * idm;
        Y[wv][lane] = y;                       // wave-synchronous: no barrier needed
        float acc = 0.f;
#pragma unroll 16
        for (int k = 0; k < 64; k++) acc = fmaf(Y[wv][k], W[k * 64 + lane], acc);
        ee[node * 64 + lane] = fmaxf(acc, 0.f);
    }
}

// one MPNN layer: msg = relu([agg | ee] @ Wm); out = relu([cur | msg] @ Wu)
__global__ __launch_bounds__(256, 2) void k_layer(
        const float* __restrict__ agg, const float* __restrict__ ee,
        const float* __restrict__ cur,
        const float* __restrict__ Wm, const float* __restrict__ Wu,
        float* __restrict__ out) {
    __shared__ float SWm[128 * 64];
    __shared__ float SWu[128 * 64];
    __shared__ __align__(16) float SIN[4][128][4];   // [wave][k][node]
    int t = threadIdx.x;
    for (int i = t; i < 8192; i += 256) { SWm[i] = Wm[i]; SWu[i] = Wu[i]; }
    __syncthreads();
    int wv = t >> 6, lane = t & 63;
    int wg = blockIdx.x * 4 + wv, nw = gridDim.x * 4;
    for (int base = wg * 4; base < N_NODES; base += nw * 4) {
        int nn[4];
#pragma unroll
        for (int m = 0; m < 4; m++) {
            int n = base + m; if (n >= N_NODES) n = base;
            nn[m] = n;
        }
#pragma unroll
        for (int m = 0; m < 4; m++) {
            SIN[wv][lane][m]      = agg[nn[m] * 64 + lane];
            SIN[wv][64 + lane][m] = ee[nn[m] * 64 + lane];
        }
        float a0 = 0, a1 = 0, a2 = 0, a3 = 0;
#pragma unroll 16
        for (int k = 0; k < 128; k++) {
            float4 v = *(const float4*)&SIN[wv][k][0];   // broadcast
            float w = SWm[k * 64 + lane];                // 2-way alias: free
            a0 = fmaf(v.x, w, a0); a1 = fmaf(v.y, w, a1);
            a2 = fmaf(v.z, w, a2); a3 = fmaf(v.w, w, a3);
        }
#pragma unroll
        for (int m = 0; m < 4; m++) SIN[wv][lane][m] = cur[nn[m] * 64 + lane];
        SIN[wv][64 + lane][0] = fmaxf(a0, 0.f);
        SIN[wv][64 + lane][1] = fmaxf(a1, 0.f);
        SIN[wv][64 + lane][2] = fmaxf(a2, 0.f);
        SIN[wv][64 + lane][3] = fmaxf(a3, 0.f);
        a0 = a1 = a2 = a3 = 0;
#pragma unroll 16
        for (int k = 0; k < 128; k++) {
            float4 v = *(const float4*)&SIN[wv][k][0];
            float w = SWu[k * 64 + lane];
            a0 = fmaf(v.x, w, a0); a1 = fmaf(v.y, w, a1);
            a2 = fmaf(v.z, w, a2); a3 = fmaf(v.w, w, a3);
        }
        float r[4] = { a0, a1, a2, a3 };
#pragma unroll
        for (int m = 0; m < 4; m++) {
            int n = base + m;
            if (n < N_NODES) out[n * 64 + lane] = fmaxf(r[m], 0.f);
        }
    }
}

// per-graph mean of cur; 20 blocks/graph, float atomics into zeroed means
__global__ void k_means(const float* __restrict__ cur, float* __restrict__ means) {
    int g = blockIdx.x / MCHUNK;
    int c = blockIdx.x % MCHUNK;
    int t = threadIdx.x, f = t & 63, q = t >> 6;
    int base = g * NPG + c * MROWS;
    float acc = 0.f;
    for (int n = base + q; n < base + MROWS; n += 4) acc += cur[n * 64 + f];
    __shared__ float red[4][64];
    red[q][f] = acc;
    __syncthreads();
    if (q == 0)
        atomicAdd(&means[g * 64 + f],
                  (red[0][f] + red[1][f] + red[2][f] + red[3][f]) * (1.0f / NPG));
}

// out[n] = b + sum_f relu((means[batch[n]] @ Wp)[f]) * Wr[f] + sum_f relu(cur[n][f]) * Wr[64+f]
__global__ __launch_bounds__(256) void k_readout(
        const float* __restrict__ cur, const float* __restrict__ means,
        const int* __restrict__ batch, const float* __restrict__ Wp,
        const float* __restrict__ Wr, const float* __restrict__ br,
        float* __restrict__ out) {
    __shared__ float W[64 * 64];
    __shared__ float R[128];
    __shared__ float GP[4][64];
    int t = threadIdx.x;
    for (int i = t; i < 4096; i += 256) W[i] = Wp[i];
    if (t < 128) R[t] = Wr[t];
    __syncthreads();
    int wv = t >> 6, lane = t & 63;
    float b = br[0];
    int wg = blockIdx.x * 4 + wv, nw = gridDim.x * 4;
    for (int node = wg; node < N_NODES; node += nw) {
        int g = batch[node];
        GP[wv][lane] = means[g * 64 + lane];
        float acc = 0.f;
#pragma unroll 16
        for (int k = 0; k < 64; k++) acc = fmaf(GP[wv][k], W[k * 64 + lane], acc);
        float v = fmaxf(acc, 0.f) * R[lane]
                + fmaxf(cur[node * 64 + lane], 0.f) * R[64 + lane];
        for (int off = 32; off; off >>= 1) v += __shfl_xor(v, off, 64);
        if (lane == 0) out[node] = v + b;
    }
}

// ---------------------------------------------------------------------------
extern "C" void kernel_launch(void* const* d_in, const int* in_sizes, int n_in,
                              void* d_out, int out_size, void* d_ws, size_t ws_size,
                              hipStream_t stream) {
    const float* x    = (const float*)d_in[0];
    const float* Wi   = (const float*)d_in[1];
    const float* We1  = (const float*)d_in[2];
    const float* We2  = (const float*)d_in[3];
    const float* Wm   = (const float*)d_in[4];   // [3,128,64]
    const float* Wu   = (const float*)d_in[5];   // [3,128,64]
    const float* Wp   = (const float*)d_in[6];
    const float* Wr   = (const float*)d_in[7];
    const float* br   = (const float*)d_in[8];
    const int*   ei   = (const int*)d_in[9];     // [2,E]
    const int*   batch= (const int*)d_in[10];
    const int* row = ei;
    const int* col = ei + N_EDGES;
    float* out = (float*)d_out;

    // workspace carve-up (256B aligned)
    char* w = (char*)d_ws;
    size_t off = 0;
    auto carve = [&](size_t bytes) -> void* {
        void* p = (void*)(w + off);
        off += (bytes + 255) & ~(size_t)255;
        return p;
    };
    int*   deg      = (int*)carve((size_t)N_NODES * 4);
    int*   rowptr   = (int*)carve((size_t)(N_NODES + 1) * 4);
    int*   cursor   = (int*)carve((size_t)N_NODES * 4);
    int*   csr      = (int*)carve((size_t)N_EDGES * 4);
    int*   partials = (int*)carve((size_t)SCAN_NBLK * 4);
    float* cur0     = (float*)carve((size_t)N_NODES * 64 * 4);
    float* cur1     = (float*)carve((size_t)N_NODES * 64 * 4);
    float* agg      = (float*)carve((size_t)N_NODES * 64 * 4);
    float* ee       = (float*)carve((size_t)N_NODES * 64 * 4);
    float* means    = (float*)carve((size_t)NG * 64 * 4);
    int*   dmax     = (int*)carve(256);

    hipMemsetAsync(deg,   0, (size_t)N_NODES * 4, stream);
    hipMemsetAsync(dmax,  0, 4, stream);
    hipMemsetAsync(means, 0, (size_t)NG * 64 * 4, stream);

    // CSR build (by destination)
    k_deg         <<<(N_EDGES + 255) / 256, 256, 0, stream>>>(col, deg);
    k_degmax      <<<(N_NODES + 255) / 256, 256, 0, stream>>>(deg, dmax);
    k_blocksum    <<<SCAN_NBLK, 256, 0, stream>>>(deg, partials);
    k_scanpartials<<<1, 256, 0, stream>>>(partials, rowptr);
    k_scanfinal   <<<SCAN_NBLK, 256, 0, stream>>>(deg, partials, rowptr, cursor);
    k_fill        <<<(N_EDGES + 255) / 256, 256, 0, stream>>>(row, col, cursor, csr);

    k_init  <<<(N_NODES * 64) / 256, 256, 0, stream>>>(x, Wi, We1, cur0, cur1); // cur1 = h

    k_gather<<<(N_NODES * 64 + 255) / 256, 256, 0, stream>>>(cur1, agg, rowptr, csr);
    k_edge_emb<<<1024, 256, 0, stream>>>(agg, deg, dmax, We2, ee);

    float* src = cur0;
    float* dst = cur1;
    for (int i = 0; i < 3; i++) {
        k_gather<<<(N_NODES * 64 + 255) / 256, 256, 0, stream>>>(src, agg, rowptr, csr);
        k_layer<<<512, 256, 0, stream>>>(agg, ee, src,
                                         Wm + (size_t)i * 128 * 64,
                                         Wu + (size_t)i * 128 * 64, dst);
        float* tmp = src; src = dst; dst = tmp;
    }

    k_means  <<<NG * MCHUNK, 256, 0, stream>>>(src, means);
    k_readout<<<1024, 256, 0, stream>>>(src, means, batch, Wp, Wr, br, out);
}

// Round 5
// 385.879 us; speedup vs baseline: 8.1114x; 1.3268x over previous
//
#include <hip/hip_runtime.h>
#include <hip/hip_bf16.h>

#define N_NODES 50000
#define N_EDGES 800000
#define NF      64
#define NG      50
#define NPG     (N_NODES / NG)   // 1000 nodes per graph
#define SCAN_NBLK ((N_NODES + 255) / 256)   // 196
#define MCHUNK  20               // blocks per graph for means
#define MROWS   (NPG / MCHUNK)   // 50 nodes per means block
#define NTILES  (N_NODES / 16)   // 3125 exact

typedef __attribute__((ext_vector_type(8))) short bf16x8;
typedef __attribute__((ext_vector_type(4))) float f32x4;

// round-half-up fp32->bf16 pair pack (inputs are finite)
__device__ inline unsigned pkbf(float a, float b) {
    unsigned ua = __float_as_uint(a) + 0x8000u;
    unsigned ub = __float_as_uint(b) + 0x8000u;
    return (ua >> 16) | (ub & 0xFFFF0000u);
}
__device__ inline short bf1(float a) {
    return (short)((__float_as_uint(a) + 0x8000u) >> 16);
}
// A-frag: 8 consecutive fp32 from global -> 8 bf16
__device__ inline bf16x8 afrag_g(const float* p) {
    float4 x = *(const float4*)p;
    float4 y = *(const float4*)(p + 4);
    union { bf16x8 v; unsigned u[4]; } r;
    r.u[0] = pkbf(x.x, x.y); r.u[1] = pkbf(x.z, x.w);
    r.u[2] = pkbf(y.x, y.y); r.u[3] = pkbf(y.z, y.w);
    return r.v;
}

// ---------------------------------------------------------------------------
__global__ void k_deg(const int* __restrict__ col, int* __restrict__ deg) {
    int e = blockIdx.x * 256 + threadIdx.x;
    if (e < N_EDGES) atomicAdd(&deg[col[e]], 1);
}

__global__ void k_degmax(const int* __restrict__ deg, int* __restrict__ dmax) {
    int i = blockIdx.x * 256 + threadIdx.x;
    int m = (i < N_NODES) ? deg[i] : 0;
    for (int off = 32; off; off >>= 1) m = max(m, __shfl_xor(m, off, 64));
    if ((threadIdx.x & 63) == 0) atomicMax(dmax, m);
}

// ---- hierarchical scan ----
__global__ void k_blocksum(const int* __restrict__ deg, int* __restrict__ partials) {
    int i = blockIdx.x * 256 + threadIdx.x;
    int v = (i < N_NODES) ? deg[i] : 0;
    for (int off = 32; off; off >>= 1) v += __shfl_xor(v, off, 64);
    __shared__ int s[4];
    if ((threadIdx.x & 63) == 0) s[threadIdx.x >> 6] = v;
    __syncthreads();
    if (threadIdx.x == 0) partials[blockIdx.x] = s[0] + s[1] + s[2] + s[3];
}

__global__ void k_scanpartials(int* __restrict__ partials, int* __restrict__ rowptr) {
    __shared__ int s[256];
    int t = threadIdx.x;
    int v = (t < SCAN_NBLK) ? partials[t] : 0;
    s[t] = v;
    __syncthreads();
    for (int off = 1; off < 256; off <<= 1) {
        int u = (t >= off) ? s[t - off] : 0;
        __syncthreads();
        s[t] += u;
        __syncthreads();
    }
    if (t < SCAN_NBLK) partials[t] = s[t] - v;
    if (t == 0) rowptr[N_NODES] = N_EDGES;
}

__global__ void k_scanfinal(const int* __restrict__ deg, const int* __restrict__ partials,
                            int* __restrict__ rowptr, int* __restrict__ cursor) {
    int t = threadIdx.x;
    int i = blockIdx.x * 256 + t;
    int v = (i < N_NODES) ? deg[i] : 0;
    __shared__ int s[256];
    s[t] = v;
    __syncthreads();
    for (int off = 1; off < 256; off <<= 1) {
        int u = (t >= off) ? s[t - off] : 0;
        __syncthreads();
        s[t] += u;
        __syncthreads();
    }
    int ex = s[t] - v + partials[blockIdx.x];
    if (i < N_NODES) { rowptr[i] = ex; cursor[i] = ex; }
}

__global__ void k_fill(const int* __restrict__ row, const int* __restrict__ col,
                       int* __restrict__ cursor, int* __restrict__ csr) {
    int e = blockIdx.x * 256 + threadIdx.x;
    if (e >= N_EDGES) return;
    int pos = atomicAdd(&cursor[col[e]], 1);
    csr[pos] = row[e];
}

// cur = relu(x @ W_init); h = relu(x @ W_e1) padded (lane63 = 0)
__global__ void k_init(const float* __restrict__ x, const float* __restrict__ Wi,
                       const float* __restrict__ We1,
                       float* __restrict__ cur, float* __restrict__ h) {
    int idx = blockIdx.x * 256 + threadIdx.x;
    int node = idx >> 6, f = idx & 63;
    if (node >= N_NODES) return;
    float4 xv = ((const float4*)x)[node];
    float c = xv.x * Wi[f] + xv.y * Wi[64 + f] + xv.z * Wi[128 + f] + xv.w * Wi[192 + f];
    cur[idx] = fmaxf(c, 0.f);
    float hv = 0.f;
    if (f < 63) {
        hv = xv.x * We1[f] + xv.y * We1[63 + f] + xv.z * We1[126 + f] + xv.w * We1[189 + f];
        hv = fmaxf(hv, 0.f);
    }
    h[idx] = hv;
}

// agg[n] = (1/deg) * sum src[row]; quarter-wave per edge slot, 4-deep ILP
__global__ void k_gather(const float* __restrict__ src, float* __restrict__ agg,
                         const int* __restrict__ rowptr, const int* __restrict__ csr) {
    int wid = (blockIdx.x * 256 + threadIdx.x) >> 6;
    if (wid >= N_NODES) return;
    int lane = threadIdx.x & 63;
    int grp = lane >> 4;
    int fl  = (lane & 15) << 2;
    int beg = rowptr[wid], end = rowptr[wid + 1];
    float4 a0 = {0,0,0,0}, a1 = {0,0,0,0};
    int j = beg + grp;
    for (; j + 12 < end; j += 16) {
        int r0 = csr[j], r1 = csr[j + 4], r2 = csr[j + 8], r3 = csr[j + 12];
        float4 v0 = *(const float4*)(src + r0 * 64 + fl);
        float4 v1 = *(const float4*)(src + r1 * 64 + fl);
        float4 v2 = *(const float4*)(src + r2 * 64 + fl);
        float4 v3 = *(const float4*)(src + r3 * 64 + fl);
        a0.x += v0.x; a0.y += v0.y; a0.z += v0.z; a0.w += v0.w;
        a1.x += v1.x; a1.y += v1.y; a1.z += v1.z; a1.w += v1.w;
        a0.x += v2.x; a0.y += v2.y; a0.z += v2.z; a0.w += v2.w;
        a1.x += v3.x; a1.y += v3.y; a1.z += v3.z; a1.w += v3.w;
    }
    for (; j < end; j += 4) {
        int r = csr[j];
        float4 v = *(const float4*)(src + r * 64 + fl);
        a0.x += v.x; a0.y += v.y; a0.z += v.z; a0.w += v.w;
    }
    a0.x += a1.x; a0.y += a1.y; a0.z += a1.z; a0.w += a1.w;
#pragma unroll
    for (int off = 16; off <= 32; off <<= 1) {
        a0.x += __shfl_xor(a0.x, off, 64);
        a0.y += __shfl_xor(a0.y, off, 64);
        a0.z += __shfl_xor(a0.z, off, 64);
        a0.w += __shfl_xor(a0.w, off, 64);
    }
    if (lane < 16) {
        float inv = 1.0f / (float)(end - beg);
        float4 o = { a0.x * inv, a0.y * inv, a0.z * inv, a0.w * inv };
        *(float4*)(agg + wid * 64 + fl) = o;
    }
}

// edge_emb via MFMA: A=[agg(63) | deg/dmax], B=We2[64][64]
__global__ __launch_bounds__(256) void k_edge_mfma(
        const float* __restrict__ agg, const int* __restrict__ deg,
        const int* __restrict__ dmax, const float* __restrict__ We2,
        float* __restrict__ ee) {
    __shared__ unsigned SB[2][4][64][4];   // [ks][tile][slot][dw] 8KB
    int t = threadIdx.x;
    for (int F = t; F < 512; F += 256) {
        int ks = F >> 8, tile = (F >> 6) & 3, ln = F & 63;
        int c = ln & 15, q = ln >> 4;
        const float* W = We2 + (ks * 32 + q * 8) * 64 + tile * 16 + c;
        unsigned d0 = pkbf(W[0],       W[64]);
        unsigned d1 = pkbf(W[2 * 64],  W[3 * 64]);
        unsigned d2 = pkbf(W[4 * 64],  W[5 * 64]);
        unsigned d3 = pkbf(W[6 * 64],  W[7 * 64]);
        int slot = ln ^ ((ln >> 3) & 7);
        SB[ks][tile][slot][0] = d0; SB[ks][tile][slot][1] = d1;
        SB[ks][tile][slot][2] = d2; SB[ks][tile][slot][3] = d3;
    }
    __syncthreads();
    int wv = t >> 6, lane = t & 63;
    int m = lane & 15, quad = lane >> 4;
    int slot = lane ^ ((lane >> 3) & 7);
    float idm = 1.0f / (float)dmax[0];
    for (int tb = blockIdx.x * 4 + wv; tb < NTILES; tb += gridDim.x * 4) {
        int base = tb * 16;
        const float* arow = agg + (size_t)(base + m) * 64;
        float dv = (float)deg[base + m] * idm;
        f32x4 acc[4];
#pragma unroll
        for (int i = 0; i < 4; i++) acc[i] = (f32x4){0.f, 0.f, 0.f, 0.f};
#pragma unroll
        for (int ks = 0; ks < 2; ks++) {
            const float* p = arow + ks * 32 + quad * 8;
            float4 x = *(const float4*)p;
            float4 y = *(const float4*)(p + 4);
            if (ks == 1 && quad == 3) y.w = dv;   // k=63 column
            union { bf16x8 v; unsigned u[4]; } a;
            a.u[0] = pkbf(x.x, x.y); a.u[1] = pkbf(x.z, x.w);
            a.u[2] = pkbf(y.x, y.y); a.u[3] = pkbf(y.z, y.w);
#pragma unroll
            for (int tile = 0; tile < 4; tile++) {
                bf16x8 b = *(const bf16x8*)&SB[ks][tile][slot][0];
                acc[tile] = __builtin_amdgcn_mfma_f32_16x16x32_bf16(a.v, b, acc[tile], 0, 0, 0);
            }
        }
#pragma unroll
        for (int tile = 0; tile < 4; tile++)
#pragma unroll
            for (int r = 0; r < 4; r++)
                ee[(size_t)(base + quad * 4 + r) * 64 + tile * 16 + m] =
                    fmaxf(acc[tile][r], 0.f);
    }
}

// MPNN layer via MFMA: msg = relu([agg|ee]@Wm); out = relu([cur|msg]@Wu)
__global__ __launch_bounds__(256) void k_layer_mfma(
        const float* __restrict__ agg, const float* __restrict__ ee,
        const float* __restrict__ cur,
        const float* __restrict__ Wm, const float* __restrict__ Wu,
        float* __restrict__ out) {
    __shared__ unsigned SB[2][4][4][64][4];   // [gemm][ks][tile][slot][dw] 32KB
    __shared__ short MT[4][16][64];           // msg bf16, swizzled f-groups, 8KB
    int t = threadIdx.x;
    for (int F = t; F < 2048; F += 256) {
        int g = F >> 10, ks = (F >> 8) & 3, tile = (F >> 6) & 3, ln = F & 63;
        int c = ln & 15, q = ln >> 4;
        const float* W = (g ? Wu : Wm) + (ks * 32 + q * 8) * 64 + tile * 16 + c;
        unsigned d0 = pkbf(W[0],      W[64]);
        unsigned d1 = pkbf(W[2 * 64], W[3 * 64]);
        unsigned d2 = pkbf(W[4 * 64], W[5 * 64]);
        unsigned d3 = pkbf(W[6 * 64], W[7 * 64]);
        int slot = ln ^ ((ln >> 3) & 7);
        SB[g][ks][tile][slot][0] = d0; SB[g][ks][tile][slot][1] = d1;
        SB[g][ks][tile][slot][2] = d2; SB[g][ks][tile][slot][3] = d3;
    }
    __syncthreads();
    int wv = t >> 6, lane = t & 63;
    int m = lane & 15, quad = lane >> 4;
    int slot = lane ^ ((lane >> 3) & 7);
    for (int tb = blockIdx.x * 4 + wv; tb < NTILES; tb += gridDim.x * 4) {
        int base = tb * 16;
        const float* arow = agg + (size_t)(base + m) * 64;
        const float* erow = ee  + (size_t)(base + m) * 64;
        const float* crow = cur + (size_t)(base + m) * 64;
        f32x4 acc[4];
#pragma unroll
        for (int i = 0; i < 4; i++) acc[i] = (f32x4){0.f, 0.f, 0.f, 0.f};
        // GEMM1: k 0..63 = agg, 64..127 = ee
#pragma unroll
        for (int ks = 0; ks < 4; ks++) {
            const float* src = (ks < 2) ? (arow + ks * 32) : (erow + (ks - 2) * 32);
            bf16x8 a = afrag_g(src + quad * 8);
#pragma unroll
            for (int tile = 0; tile < 4; tile++) {
                bf16x8 b = *(const bf16x8*)&SB[0][ks][tile][slot][0];
                acc[tile] = __builtin_amdgcn_mfma_f32_16x16x32_bf16(a, b, acc[tile], 0, 0, 0);
            }
        }
        // relu(msg) -> MT in A-readable swizzled layout (wave-private, no barrier)
#pragma unroll
        for (int tile = 0; tile < 4; tile++)
#pragma unroll
            for (int r = 0; r < 4; r++) {
                int node = quad * 4 + r;
                int f = tile * 16 + m;
                int sidx = (((f >> 3) ^ (node & 7)) << 3) | (f & 7);
                MT[wv][node][sidx] = bf1(fmaxf(acc[tile][r], 0.f));
            }
        // GEMM2: k 0..63 = cur (global), 64..127 = msg (LDS)
#pragma unroll
        for (int i = 0; i < 4; i++) acc[i] = (f32x4){0.f, 0.f, 0.f, 0.f};
#pragma unroll
        for (int ks = 0; ks < 4; ks++) {
            bf16x8 a;
            if (ks < 2) {
                a = afrag_g(crow + ks * 32 + quad * 8);
            } else {
                int gp = ((ks - 2) * 4 + quad) ^ (m & 7);
                a = *(const bf16x8*)&MT[wv][m][gp << 3];
            }
#pragma unroll
            for (int tile = 0; tile < 4; tile++) {
                bf16x8 b = *(const bf16x8*)&SB[1][ks][tile][slot][0];
                acc[tile] = __builtin_amdgcn_mfma_f32_16x16x32_bf16(a, b, acc[tile], 0, 0, 0);
            }
        }
#pragma unroll
        for (int tile = 0; tile < 4; tile++)
#pragma unroll
            for (int r = 0; r < 4; r++)
                out[(size_t)(base + quad * 4 + r) * 64 + tile * 16 + m] =
                    fmaxf(acc[tile][r], 0.f);
    }
}

// per-graph mean of cur; 20 blocks/graph, atomics into zeroed means
__global__ void k_means(const float* __restrict__ cur, float* __restrict__ means) {
    int g = blockIdx.x / MCHUNK;
    int c = blockIdx.x % MCHUNK;
    int t = threadIdx.x, f = t & 63, q = t >> 6;
    int base = g * NPG + c * MROWS;
    float acc = 0.f;
    for (int n = base + q; n < base + MROWS; n += 4) acc += cur[n * 64 + f];
    __shared__ float red[4][64];
    red[q][f] = acc;
    __syncthreads();
    if (q == 0)
        atomicAdd(&means[g * 64 + f],
                  (red[0][f] + red[1][f] + red[2][f] + red[3][f]) * (1.0f / NPG));
}

// r1[g] = sum_f relu((means[g] @ Wp)[f]) * Wr[f]  -- 50 graphs, 1 block
__global__ __launch_bounds__(256) void k_pool(
        const float* __restrict__ means, const float* __restrict__ Wp,
        const float* __restrict__ Wr, float* __restrict__ r1) {
    int wv = threadIdx.x >> 6, lane = threadIdx.x & 63;
    for (int g = wv; g < NG; g += 4) {
        float acc = 0.f;
#pragma unroll 16
        for (int k = 0; k < 64; k++) acc = fmaf(means[g * 64 + k], Wp[k * 64 + lane], acc);
        float v = fmaxf(acc, 0.f) * Wr[lane];
        for (int off = 32; off; off >>= 1) v += __shfl_xor(v, off, 64);
        if (lane == 0) r1[g] = v;
    }
}

// out[n] = b + r1[batch[n]] + dot(relu(cur[n]), Wr[64:])  -- quarter-wave per node
__global__ void k_read2(const float* __restrict__ cur, const float* __restrict__ r1,
                        const int* __restrict__ batch, const float* __restrict__ Wr,
                        const float* __restrict__ br, float* __restrict__ out) {
    int idx = blockIdx.x * 256 + threadIdx.x;
    int node = idx >> 4;
    if (node >= N_NODES) return;
    int q = idx & 15;
    float4 c = *(const float4*)(cur + (size_t)node * 64 + q * 4);
    float4 w = *(const float4*)(Wr + 64 + q * 4);
    float v = fmaxf(c.x, 0.f) * w.x + fmaxf(c.y, 0.f) * w.y
            + fmaxf(c.z, 0.f) * w.z + fmaxf(c.w, 0.f) * w.w;
    v += __shfl_xor(v, 1, 64); v += __shfl_xor(v, 2, 64);
    v += __shfl_xor(v, 4, 64); v += __shfl_xor(v, 8, 64);
    if (q == 0) out[node] = v + r1[batch[node]] + br[0];
}

// ---------------------------------------------------------------------------
extern "C" void kernel_launch(void* const* d_in, const int* in_sizes, int n_in,
                              void* d_out, int out_size, void* d_ws, size_t ws_size,
                              hipStream_t stream) {
    const float* x    = (const float*)d_in[0];
    const float* Wi   = (const float*)d_in[1];
    const float* We1  = (const float*)d_in[2];
    const float* We2  = (const float*)d_in[3];
    const float* Wm   = (const float*)d_in[4];   // [3,128,64]
    const float* Wu   = (const float*)d_in[5];   // [3,128,64]
    const float* Wp   = (const float*)d_in[6];
    const float* Wr   = (const float*)d_in[7];
    const float* br   = (const float*)d_in[8];
    const int*   ei   = (const int*)d_in[9];     // [2,E]
    const int*   batch= (const int*)d_in[10];
    const int* row = ei;
    const int* col = ei + N_EDGES;
    float* out = (float*)d_out;

    char* w = (char*)d_ws;
    size_t off = 0;
    auto carve = [&](size_t bytes) -> void* {
        void* p = (void*)(w + off);
        off += (bytes + 255) & ~(size_t)255;
        return p;
    };
    int*   deg      = (int*)carve((size_t)N_NODES * 4);
    int*   rowptr   = (int*)carve((size_t)(N_NODES + 1) * 4);
    int*   cursor   = (int*)carve((size_t)N_NODES * 4);
    int*   csr      = (int*)carve((size_t)N_EDGES * 4);
    int*   partials = (int*)carve((size_t)SCAN_NBLK * 4);
    float* cur0     = (float*)carve((size_t)N_NODES * 64 * 4);
    float* cur1     = (float*)carve((size_t)N_NODES * 64 * 4);
    float* agg      = (float*)carve((size_t)N_NODES * 64 * 4);
    float* ee       = (float*)carve((size_t)N_NODES * 64 * 4);
    float* means    = (float*)carve((size_t)NG * 64 * 4);
    float* r1       = (float*)carve((size_t)NG * 4);
    int*   dmax     = (int*)carve(256);

    hipMemsetAsync(deg,   0, (size_t)N_NODES * 4, stream);
    hipMemsetAsync(dmax,  0, 4, stream);
    hipMemsetAsync(means, 0, (size_t)NG * 64 * 4, stream);

    k_deg         <<<(N_EDGES + 255) / 256, 256, 0, stream>>>(col, deg);
    k_degmax      <<<(N_NODES + 255) / 256, 256, 0, stream>>>(deg, dmax);
    k_blocksum    <<<SCAN_NBLK, 256, 0, stream>>>(deg, partials);
    k_scanpartials<<<1, 256, 0, stream>>>(partials, rowptr);
    k_scanfinal   <<<SCAN_NBLK, 256, 0, stream>>>(deg, partials, rowptr, cursor);
    k_fill        <<<(N_EDGES + 255) / 256, 256, 0, stream>>>(row, col, cursor, csr);

    k_init  <<<(N_NODES * 64) / 256, 256, 0, stream>>>(x, Wi, We1, cur0, cur1); // cur1 = h

    k_gather<<<(N_NODES * 64 + 255) / 256, 256, 0, stream>>>(cur1, agg, rowptr, csr);
    k_edge_mfma<<<392, 256, 0, stream>>>(agg, deg, dmax, We2, ee);

    float* src = cur0;
    float* dst = cur1;
    for (int i = 0; i < 3; i++) {
        k_gather<<<(N_NODES * 64 + 255) / 256, 256, 0, stream>>>(src, agg, rowptr, csr);
        k_layer_mfma<<<392, 256, 0, stream>>>(agg, ee, src,
                                              Wm + (size_t)i * 128 * 64,
                                              Wu + (size_t)i * 128 * 64, dst);
        float* tmp = src; src = dst; dst = tmp;
    }

    k_means<<<NG * MCHUNK, 256, 0, stream>>>(src, means);
    k_pool <<<1, 256, 0, stream>>>(means, Wp, Wr, r1);
    k_read2<<<(N_NODES * 16 + 255) / 256, 256, 0, stream>>>(src, r1, batch, Wr, br, out);
}

// Round 7
// 384.944 us; speedup vs baseline: 8.1311x; 1.0024x over previous
//
#include <hip/hip_runtime.h>
#include <hip/hip_bf16.h>

#define N_NODES 50000
#define N_EDGES 800000
#define NF      64
#define NG      50
#define NPG     (N_NODES / NG)   // 1000 nodes per graph
#define SCAN_NBLK ((N_NODES + 255) / 256)   // 196
#define MCHUNK  20               // blocks per graph for means
#define MROWS   (NPG / MCHUNK)   // 50 nodes per means block
#define NTILES  (N_NODES / 16)   // 3125 exact

typedef __attribute__((ext_vector_type(8))) short bf16x8;
typedef __attribute__((ext_vector_type(4))) float f32x4;

// round-half-up fp32->bf16 pair pack (inputs are finite)
__device__ inline unsigned pkbf(float a, float b) {
    unsigned ua = __float_as_uint(a) + 0x8000u;
    unsigned ub = __float_as_uint(b) + 0x8000u;
    return (ua >> 16) | (ub & 0xFFFF0000u);
}
__device__ inline short bf1(float a) {
    return (short)((__float_as_uint(a) + 0x8000u) >> 16);
}
// A-frag: 8 consecutive fp32 from global -> 8 bf16
__device__ inline bf16x8 afrag_g(const float* p) {
    float4 x = *(const float4*)p;
    float4 y = *(const float4*)(p + 4);
    union { bf16x8 v; unsigned u[4]; } r;
    r.u[0] = pkbf(x.x, x.y); r.u[1] = pkbf(x.z, x.w);
    r.u[2] = pkbf(y.x, y.y); r.u[3] = pkbf(y.z, y.w);
    return r.v;
}

// ---------------------------------------------------------------------------
__global__ void k_deg(const int* __restrict__ col, int* __restrict__ deg) {
    int e = blockIdx.x * 256 + threadIdx.x;
    if (e < N_EDGES) atomicAdd(&deg[col[e]], 1);
}

// ---- hierarchical scan (+ degmax folded in) ----
__global__ void k_blocksum(const int* __restrict__ deg, int* __restrict__ partials,
                           int* __restrict__ dmax) {
    int i = blockIdx.x * 256 + threadIdx.x;
    int d = (i < N_NODES) ? deg[i] : 0;
    int v = d, m = d;
    for (int off = 32; off; off >>= 1) {
        v += __shfl_xor(v, off, 64);
        m = max(m, __shfl_xor(m, off, 64));
    }
    __shared__ int s[4];
    if ((threadIdx.x & 63) == 0) {
        s[threadIdx.x >> 6] = v;
        atomicMax(dmax, m);
    }
    __syncthreads();
    if (threadIdx.x == 0) partials[blockIdx.x] = s[0] + s[1] + s[2] + s[3];
}

__global__ void k_scanpartials(int* __restrict__ partials, int* __restrict__ rowptr) {
    __shared__ int s[256];
    int t = threadIdx.x;
    int v = (t < SCAN_NBLK) ? partials[t] : 0;
    s[t] = v;
    __syncthreads();
    for (int off = 1; off < 256; off <<= 1) {
        int u = (t >= off) ? s[t - off] : 0;
        __syncthreads();
        s[t] += u;
        __syncthreads();
    }
    if (t < SCAN_NBLK) partials[t] = s[t] - v;
    if (t == 0) rowptr[N_NODES] = N_EDGES;
}

__global__ void k_scanfinal(const int* __restrict__ deg, const int* __restrict__ partials,
                            int* __restrict__ rowptr, int* __restrict__ cursor) {
    int t = threadIdx.x;
    int i = blockIdx.x * 256 + t;
    int v = (i < N_NODES) ? deg[i] : 0;
    __shared__ int s[256];
    s[t] = v;
    __syncthreads();
    for (int off = 1; off < 256; off <<= 1) {
        int u = (t >= off) ? s[t - off] : 0;
        __syncthreads();
        s[t] += u;
        __syncthreads();
    }
    int ex = s[t] - v + partials[blockIdx.x];
    if (i < N_NODES) { rowptr[i] = ex; cursor[i] = ex; }
}

__global__ void k_fill(const int* __restrict__ row, const int* __restrict__ col,
                       int* __restrict__ cursor, int* __restrict__ csr) {
    int e = blockIdx.x * 256 + threadIdx.x;
    if (e >= N_EDGES) return;
    int pos = atomicAdd(&cursor[col[e]], 1);
    csr[pos] = row[e];
}

// cur = relu(x @ W_init); h = relu(x @ W_e1) padded (lane63 = 0)
__global__ void k_init(const float* __restrict__ x, const float* __restrict__ Wi,
                       const float* __restrict__ We1,
                       float* __restrict__ cur, float* __restrict__ h) {
    int idx = blockIdx.x * 256 + threadIdx.x;
    int node = idx >> 6, f = idx & 63;
    if (node >= N_NODES) return;
    float4 xv = ((const float4*)x)[node];
    float c = xv.x * Wi[f] + xv.y * Wi[64 + f] + xv.z * Wi[128 + f] + xv.w * Wi[192 + f];
    cur[idx] = fmaxf(c, 0.f);
    float hv = 0.f;
    if (f < 63) {
        hv = xv.x * We1[f] + xv.y * We1[63 + f] + xv.z * We1[126 + f] + xv.w * We1[189 + f];
        hv = fmaxf(hv, 0.f);
    }
    h[idx] = hv;
}

// agg[n] = (1/deg) * sum src[row]
// one wave per node; one coalesced csr load per 64 edges; indices broadcast via
// __shfl. CRITICAL: cnt is wave-uniform, so the shuffle loop trip count is
// uniform and every lane executes every __shfl (ds_bpermute reads from
// inactive lanes return 0 -> must not diverge around shuffles). Loads and
// accumulates are predicated per quarter-wave group instead.
__global__ void k_gather(const float* __restrict__ src, float* __restrict__ agg,
                         const int* __restrict__ rowptr, const int* __restrict__ csr) {
    int wid = (blockIdx.x * 256 + threadIdx.x) >> 6;
    if (wid >= N_NODES) return;
    int lane = threadIdx.x & 63;
    int grp = lane >> 4;
    int fl  = (lane & 15) << 2;
    int beg = rowptr[wid], end = rowptr[wid + 1];
    int deg = end - beg;
    float4 a0 = {0,0,0,0}, a1 = {0,0,0,0};
    for (int base = 0; base < deg; base += 64) {
        int cnt = min(64, deg - base);               // wave-uniform
        int r_lane = (base + lane < deg) ? csr[beg + base + lane] : 0;
        int nIter = (cnt + 15) >> 4;                 // wave-uniform trip count
        for (int it = 0; it < nIter; it++) {
            int j = it * 16 + grp;
            // all 64 lanes execute all shuffles (no divergence here)
            int ra = __shfl(r_lane, j,      64);
            int rb = __shfl(r_lane, j + 4,  64);
            int rc = __shfl(r_lane, j + 8,  64);
            int rd = __shfl(r_lane, j + 12, 64);
            if (j < cnt) {
                float4 v = *(const float4*)(src + (size_t)ra * 64 + fl);
                a0.x += v.x; a0.y += v.y; a0.z += v.z; a0.w += v.w;
            }
            if (j + 4 < cnt) {
                float4 v = *(const float4*)(src + (size_t)rb * 64 + fl);
                a1.x += v.x; a1.y += v.y; a1.z += v.z; a1.w += v.w;
            }
            if (j + 8 < cnt) {
                float4 v = *(const float4*)(src + (size_t)rc * 64 + fl);
                a0.x += v.x; a0.y += v.y; a0.z += v.z; a0.w += v.w;
            }
            if (j + 12 < cnt) {
                float4 v = *(const float4*)(src + (size_t)rd * 64 + fl);
                a1.x += v.x; a1.y += v.y; a1.z += v.z; a1.w += v.w;
            }
        }
    }
    a0.x += a1.x; a0.y += a1.y; a0.z += a1.z; a0.w += a1.w;
#pragma unroll
    for (int off = 16; off <= 32; off <<= 1) {
        a0.x += __shfl_xor(a0.x, off, 64);
        a0.y += __shfl_xor(a0.y, off, 64);
        a0.z += __shfl_xor(a0.z, off, 64);
        a0.w += __shfl_xor(a0.w, off, 64);
    }
    if (lane < 16) {
        float inv = 1.0f / (float)deg;
        float4 o = { a0.x * inv, a0.y * inv, a0.z * inv, a0.w * inv };
        *(float4*)(agg + wid * 64 + fl) = o;
    }
}

// edge_emb via MFMA: A=[agg(63) | deg/dmax], B=We2[64][64]
__global__ __launch_bounds__(256) void k_edge_mfma(
        const float* __restrict__ agg, const int* __restrict__ deg,
        const int* __restrict__ dmax, const float* __restrict__ We2,
        float* __restrict__ ee) {
    __shared__ unsigned SB[2][4][64][4];   // [ks][tile][slot][dw] 8KB
    int t = threadIdx.x;
    for (int F = t; F < 512; F += 256) {
        int ks = F >> 8, tile = (F >> 6) & 3, ln = F & 63;
        int c = ln & 15, q = ln >> 4;
        const float* W = We2 + (ks * 32 + q * 8) * 64 + tile * 16 + c;
        unsigned d0 = pkbf(W[0],       W[64]);
        unsigned d1 = pkbf(W[2 * 64],  W[3 * 64]);
        unsigned d2 = pkbf(W[4 * 64],  W[5 * 64]);
        unsigned d3 = pkbf(W[6 * 64],  W[7 * 64]);
        int slot = ln ^ ((ln >> 3) & 7);
        SB[ks][tile][slot][0] = d0; SB[ks][tile][slot][1] = d1;
        SB[ks][tile][slot][2] = d2; SB[ks][tile][slot][3] = d3;
    }
    __syncthreads();
    int wv = t >> 6, lane = t & 63;
    int m = lane & 15, quad = lane >> 4;
    int slot = lane ^ ((lane >> 3) & 7);
    float idm = 1.0f / (float)dmax[0];
    for (int tb = blockIdx.x * 4 + wv; tb < NTILES; tb += gridDim.x * 4) {
        int base = tb * 16;
        const float* arow = agg + (size_t)(base + m) * 64;
        float dv = (float)deg[base + m] * idm;
        f32x4 acc[4];
#pragma unroll
        for (int i = 0; i < 4; i++) acc[i] = (f32x4){0.f, 0.f, 0.f, 0.f};
#pragma unroll
        for (int ks = 0; ks < 2; ks++) {
            const float* p = arow + ks * 32 + quad * 8;
            float4 x = *(const float4*)p;
            float4 y = *(const float4*)(p + 4);
            if (ks == 1 && quad == 3) y.w = dv;   // k=63 column
            union { bf16x8 v; unsigned u[4]; } a;
            a.u[0] = pkbf(x.x, x.y); a.u[1] = pkbf(x.z, x.w);
            a.u[2] = pkbf(y.x, y.y); a.u[3] = pkbf(y.z, y.w);
#pragma unroll
            for (int tile = 0; tile < 4; tile++) {
                bf16x8 b = *(const bf16x8*)&SB[ks][tile][slot][0];
                acc[tile] = __builtin_amdgcn_mfma_f32_16x16x32_bf16(a.v, b, acc[tile], 0, 0, 0);
            }
        }
#pragma unroll
        for (int tile = 0; tile < 4; tile++)
#pragma unroll
            for (int r = 0; r < 4; r++)
                ee[(size_t)(base + quad * 4 + r) * 64 + tile * 16 + m] =
                    fmaxf(acc[tile][r], 0.f);
    }
}

// MPNN layer via MFMA: msg = relu([agg|ee]@Wm); out = relu([cur|msg]@Wu)
__global__ __launch_bounds__(256) void k_layer_mfma(
        const float* __restrict__ agg, const float* __restrict__ ee,
        const float* __restrict__ cur,
        const float* __restrict__ Wm, const float* __restrict__ Wu,
        float* __restrict__ out) {
    __shared__ unsigned SB[2][4][4][64][4];   // [gemm][ks][tile][slot][dw] 32KB
    __shared__ short MT[4][16][64];           // msg bf16, swizzled f-groups, 8KB
    int t = threadIdx.x;
    for (int F = t; F < 2048; F += 256) {
        int g = F >> 10, ks = (F >> 8) & 3, tile = (F >> 6) & 3, ln = F & 63;
        int c = ln & 15, q = ln >> 4;
        const float* W = (g ? Wu : Wm) + (ks * 32 + q * 8) * 64 + tile * 16 + c;
        unsigned d0 = pkbf(W[0],      W[64]);
        unsigned d1 = pkbf(W[2 * 64], W[3 * 64]);
        unsigned d2 = pkbf(W[4 * 64], W[5 * 64]);
        unsigned d3 = pkbf(W[6 * 64], W[7 * 64]);
        int slot = ln ^ ((ln >> 3) & 7);
        SB[g][ks][tile][slot][0] = d0; SB[g][ks][tile][slot][1] = d1;
        SB[g][ks][tile][slot][2] = d2; SB[g][ks][tile][slot][3] = d3;
    }
    __syncthreads();
    int wv = t >> 6, lane = t & 63;
    int m = lane & 15, quad = lane >> 4;
    int slot = lane ^ ((lane >> 3) & 7);
    for (int tb = blockIdx.x * 4 + wv; tb < NTILES; tb += gridDim.x * 4) {
        int base = tb * 16;
        const float* arow = agg + (size_t)(base + m) * 64;
        const float* erow = ee  + (size_t)(base + m) * 64;
        const float* crow = cur + (size_t)(base + m) * 64;
        f32x4 acc[4];
#pragma unroll
        for (int i = 0; i < 4; i++) acc[i] = (f32x4){0.f, 0.f, 0.f, 0.f};
        // GEMM1: k 0..63 = agg, 64..127 = ee
#pragma unroll
        for (int ks = 0; ks < 4; ks++) {
            const float* src = (ks < 2) ? (arow + ks * 32) : (erow + (ks - 2) * 32);
            bf16x8 a = afrag_g(src + quad * 8);
#pragma unroll
            for (int tile = 0; tile < 4; tile++) {
                bf16x8 b = *(const bf16x8*)&SB[0][ks][tile][slot][0];
                acc[tile] = __builtin_amdgcn_mfma_f32_16x16x32_bf16(a, b, acc[tile], 0, 0, 0);
            }
        }
        // relu(msg) -> MT in A-readable swizzled layout (wave-private, no barrier)
#pragma unroll
        for (int tile = 0; tile < 4; tile++)
#pragma unroll
            for (int r = 0; r < 4; r++) {
                int node = quad * 4 + r;
                int f = tile * 16 + m;
                int sidx = (((f >> 3) ^ (node & 7)) << 3) | (f & 7);
                MT[wv][node][sidx] = bf1(fmaxf(acc[tile][r], 0.f));
            }
        // GEMM2: k 0..63 = cur (global), 64..127 = msg (LDS)
#pragma unroll
        for (int i = 0; i < 4; i++) acc[i] = (f32x4){0.f, 0.f, 0.f, 0.f};
#pragma unroll
        for (int ks = 0; ks < 4; ks++) {
            bf16x8 a;
            if (ks < 2) {
                a = afrag_g(crow + ks * 32 + quad * 8);
            } else {
                int gp = ((ks - 2) * 4 + quad) ^ (m & 7);
                a = *(const bf16x8*)&MT[wv][m][gp << 3];
            }
#pragma unroll
            for (int tile = 0; tile < 4; tile++) {
                bf16x8 b = *(const bf16x8*)&SB[1][ks][tile][slot][0];
                acc[tile] = __builtin_amdgcn_mfma_f32_16x16x32_bf16(a, b, acc[tile], 0, 0, 0);
            }
        }
#pragma unroll
        for (int tile = 0; tile < 4; tile++)
#pragma unroll
            for (int r = 0; r < 4; r++)
                out[(size_t)(base + quad * 4 + r) * 64 + tile * 16 + m] =
                    fmaxf(acc[tile][r], 0.f);
    }
}

// per-graph mean of cur; 20 blocks/graph, atomics into zeroed means
__global__ void k_means(const float* __restrict__ cur, float* __restrict__ means) {
    int g = blockIdx.x / MCHUNK;
    int c = blockIdx.x % MCHUNK;
    int t = threadIdx.x, f = t & 63, q = t >> 6;
    int base = g * NPG + c * MROWS;
    float acc = 0.f;
    for (int n = base + q; n < base + MROWS; n += 4) acc += cur[n * 64 + f];
    __shared__ float red[4][64];
    red[q][f] = acc;
    __syncthreads();
    if (q == 0)
        atomicAdd(&means[g * 64 + f],
                  (red[0][f] + red[1][f] + red[2][f] + red[3][f]) * (1.0f / NPG));
}

// r1[g] = sum_f relu((means[g] @ Wp)[f]) * Wr[f]  -- 50 graphs, 1 block
__global__ __launch_bounds__(256) void k_pool(
        const float* __restrict__ means, const float* __restrict__ Wp,
        const float* __restrict__ Wr, float* __restrict__ r1) {
    int wv = threadIdx.x >> 6, lane = threadIdx.x & 63;
    for (int g = wv; g < NG; g += 4) {
        float acc = 0.f;
#pragma unroll 16
        for (int k = 0; k < 64; k++) acc = fmaf(means[g * 64 + k], Wp[k * 64 + lane], acc);
        float v = fmaxf(acc, 0.f) * Wr[lane];
        for (int off = 32; off; off >>= 1) v += __shfl_xor(v, off, 64);
        if (lane == 0) r1[g] = v;
    }
}

// out[n] = b + r1[batch[n]] + dot(relu(cur[n]), Wr[64:])  -- quarter-wave per node
__global__ void k_read2(const float* __restrict__ cur, const float* __restrict__ r1,
                        const int* __restrict__ batch, const float* __restrict__ Wr,
                        const float* __restrict__ br, float* __restrict__ out) {
    int idx = blockIdx.x * 256 + threadIdx.x;
    int node = idx >> 4;
    if (node >= N_NODES) return;
    int q = idx & 15;
    float4 c = *(const float4*)(cur + (size_t)node * 64 + q * 4);
    float4 w = *(const float4*)(Wr + 64 + q * 4);
    float v = fmaxf(c.x, 0.f) * w.x + fmaxf(c.y, 0.f) * w.y
            + fmaxf(c.z, 0.f) * w.z + fmaxf(c.w, 0.f) * w.w;
    v += __shfl_xor(v, 1, 64); v += __shfl_xor(v, 2, 64);
    v += __shfl_xor(v, 4, 64); v += __shfl_xor(v, 8, 64);
    if (q == 0) out[node] = v + r1[batch[node]] + br[0];
}

// ---------------------------------------------------------------------------
extern "C" void kernel_launch(void* const* d_in, const int* in_sizes, int n_in,
                              void* d_out, int out_size, void* d_ws, size_t ws_size,
                              hipStream_t stream) {
    const float* x    = (const float*)d_in[0];
    const float* Wi   = (const float*)d_in[1];
    const float* We1  = (const float*)d_in[2];
    const float* We2  = (const float*)d_in[3];
    const float* Wm   = (const float*)d_in[4];   // [3,128,64]
    const float* Wu   = (const float*)d_in[5];   // [3,128,64]
    const float* Wp   = (const float*)d_in[6];
    const float* Wr   = (const float*)d_in[7];
    const float* br   = (const float*)d_in[8];
    const int*   ei   = (const int*)d_in[9];     // [2,E]
    const int*   batch= (const int*)d_in[10];
    const int* row = ei;
    const int* col = ei + N_EDGES;
    float* out = (float*)d_out;

    char* w = (char*)d_ws;
    size_t off = 0;
    auto carve = [&](size_t bytes) -> void* {
        void* p = (void*)(w + off);
        off += (bytes + 255) & ~(size_t)255;
        return p;
    };
    int*   deg      = (int*)carve((size_t)N_NODES * 4);
    int*   rowptr   = (int*)carve((size_t)(N_NODES + 1) * 4);
    int*   cursor   = (int*)carve((size_t)N_NODES * 4);
    int*   csr      = (int*)carve((size_t)N_EDGES * 4);
    int*   partials = (int*)carve((size_t)SCAN_NBLK * 4);
    float* cur0     = (float*)carve((size_t)N_NODES * 64 * 4);
    float* cur1     = (float*)carve((size_t)N_NODES * 64 * 4);
    float* agg      = (float*)carve((size_t)N_NODES * 64 * 4);
    float* ee       = (float*)carve((size_t)N_NODES * 64 * 4);
    float* means    = (float*)carve((size_t)NG * 64 * 4);
    float* r1       = (float*)carve((size_t)NG * 4);
    int*   dmax     = (int*)carve(256);

    hipMemsetAsync(deg,   0, (size_t)N_NODES * 4, stream);
    hipMemsetAsync(dmax,  0, 4, stream);
    hipMemsetAsync(means, 0, (size_t)NG * 64 * 4, stream);

    k_deg         <<<(N_EDGES + 255) / 256, 256, 0, stream>>>(col, deg);
    k_blocksum    <<<SCAN_NBLK, 256, 0, stream>>>(deg, partials, dmax);
    k_scanpartials<<<1, 256, 0, stream>>>(partials, rowptr);
    k_scanfinal   <<<SCAN_NBLK, 256, 0, stream>>>(deg, partials, rowptr, cursor);
    k_fill        <<<(N_EDGES + 255) / 256, 256, 0, stream>>>(row, col, cursor, csr);

    k_init  <<<(N_NODES * 64) / 256, 256, 0, stream>>>(x, Wi, We1, cur0, cur1); // cur1 = h

    k_gather<<<(N_NODES * 64 + 255) / 256, 256, 0, stream>>>(cur1, agg, rowptr, csr);
    k_edge_mfma<<<392, 256, 0, stream>>>(agg, deg, dmax, We2, ee);

    float* src = cur0;
    float* dst = cur1;
    for (int i = 0; i < 3; i++) {
        k_gather<<<(N_NODES * 64 + 255) / 256, 256, 0, stream>>>(src, agg, rowptr, csr);
        k_layer_mfma<<<392, 256, 0, stream>>>(agg, ee, src,
                                              Wm + (size_t)i * 128 * 64,
                                              Wu + (size_t)i * 128 * 64, dst);
        float* tmp = src; src = dst; dst = tmp;
    }

    k_means<<<NG * MCHUNK, 256, 0, stream>>>(src, means);
    k_pool <<<1, 256, 0, stream>>>(means, Wp, Wr, r1);
    k_read2<<<(N_NODES * 16 + 255) / 256, 256, 0, stream>>>(src, r1, batch, Wr, br, out);
}

// Round 9
// 347.574 us; speedup vs baseline: 9.0053x; 1.1075x over previous
//
#include <hip/hip_runtime.h>
#include <hip/hip_bf16.h>

#define N_NODES 50000
#define N_EDGES 800000
#define NF      64
#define NG      50
#define NPG     (N_NODES / NG)   // 1000 nodes per graph
#define SCAN_NBLK ((N_NODES + 255) / 256)   // 196
#define MCHUNK  20               // blocks per graph for means
#define MROWS   (NPG / MCHUNK)   // 50 nodes per means block
#define NTILES  (N_NODES / 16)   // 3125 exact
#define FP_CHUNKS 112
#define FP_CHSZ  ((N_EDGES + FP_CHUNKS - 1) / FP_CHUNKS)   // 7143
#define FP_NPP   (N_NODES / 8)   // 6250 nodes per partition

typedef __attribute__((ext_vector_type(8))) short bf16x8;
typedef __attribute__((ext_vector_type(4))) float f32x4;
typedef unsigned short u16;

// round-half-up fp32->bf16 pair pack (inputs are finite)
__device__ inline unsigned pkbf(float a, float b) {
    unsigned ua = __float_as_uint(a) + 0x8000u;
    unsigned ub = __float_as_uint(b) + 0x8000u;
    return (ua >> 16) | (ub & 0xFFFF0000u);
}
__device__ inline short bf1(float a) {
    return (short)((__float_as_uint(a) + 0x8000u) >> 16);
}
__device__ inline float lo2f(unsigned u) { return __uint_as_float(u << 16); }
__device__ inline float hi2f(unsigned u) { return __uint_as_float(u & 0xFFFF0000u); }

// ---------------------------------------------------------------------------
// degree histogram, destination-partitioned: block b handles partition b&7
__global__ void k_deg(const int* __restrict__ col, int* __restrict__ deg) {
    int part = blockIdx.x & 7, chunk = blockIdx.x >> 3;
    int lo = part * FP_NPP, hi = lo + FP_NPP;
    int e0 = chunk * FP_CHSZ;
    int e1 = min(N_EDGES, e0 + FP_CHSZ);
    for (int e = e0 + threadIdx.x; e < e1; e += 256) {
        int c = col[e];
        if (c >= lo && c < hi) atomicAdd(&deg[c], 1);
    }
}

// ---- hierarchical scan (+ degmax folded in) ----
__global__ void k_blocksum(const int* __restrict__ deg, int* __restrict__ partials,
                           int* __restrict__ dmax) {
    int i = blockIdx.x * 256 + threadIdx.x;
    int d = (i < N_NODES) ? deg[i] : 0;
    int v = d, m = d;
    for (int off = 32; off; off >>= 1) {
        v += __shfl_xor(v, off, 64);
        m = max(m, __shfl_xor(m, off, 64));
    }
    __shared__ int s[4];
    if ((threadIdx.x & 63) == 0) {
        s[threadIdx.x >> 6] = v;
        atomicMax(dmax, m);
    }
    __syncthreads();
    if (threadIdx.x == 0) partials[blockIdx.x] = s[0] + s[1] + s[2] + s[3];
}

__global__ void k_scanpartials(int* __restrict__ partials, int* __restrict__ rowptr) {
    __shared__ int s[256];
    int t = threadIdx.x;
    int v = (t < SCAN_NBLK) ? partials[t] : 0;
    s[t] = v;
    __syncthreads();
    for (int off = 1; off < 256; off <<= 1) {
        int u = (t >= off) ? s[t - off] : 0;
        __syncthreads();
        s[t] += u;
        __syncthreads();
    }
    if (t < SCAN_NBLK) partials[t] = s[t] - v;
    if (t == 0) rowptr[N_NODES] = N_EDGES;
}

__global__ void k_scanfinal(const int* __restrict__ deg, const int* __restrict__ partials,
                            int* __restrict__ rowptr, int* __restrict__ cursor) {
    int t = threadIdx.x;
    int i = blockIdx.x * 256 + t;
    int v = (i < N_NODES) ? deg[i] : 0;
    __shared__ int s[256];
    s[t] = v;
    __syncthreads();
    for (int off = 1; off < 256; off <<= 1) {
        int u = (t >= off) ? s[t - off] : 0;
        __syncthreads();
        s[t] += u;
        __syncthreads();
    }
    int ex = s[t] - v + partials[blockIdx.x];
    if (i < N_NODES) { rowptr[i] = ex; cursor[i] = ex; }
}

// CSR fill, destination-partitioned: each csr line written by one partition
// (round-robin -> one XCD), killing cross-XCD 64B-line write amplification.
__global__ void k_fill(const int* __restrict__ row, const int* __restrict__ col,
                       int* __restrict__ cursor, int* __restrict__ csr) {
    int part = blockIdx.x & 7, chunk = blockIdx.x >> 3;
    int lo = part * FP_NPP, hi = lo + FP_NPP;
    int e0 = chunk * FP_CHSZ;
    int e1 = min(N_EDGES, e0 + FP_CHSZ);
    for (int e = e0 + threadIdx.x; e < e1; e += 256) {
        int c = col[e];
        if (c >= lo && c < hi) {
            int pos = atomicAdd(&cursor[c], 1);
            csr[pos] = row[e];
        }
    }
}

// cur = relu(x @ W_init) bf16[N,64]; h = relu(x @ W_e1) bf16[N,64] (lane63=0)
__global__ void k_init(const float* __restrict__ x, const float* __restrict__ Wi,
                       const float* __restrict__ We1,
                       u16* __restrict__ cur, u16* __restrict__ h) {
    int idx = blockIdx.x * 256 + threadIdx.x;   // N*32
    int node = idx >> 5, q = idx & 31;
    if (node >= N_NODES) return;
    int f0 = 2 * q, f1 = 2 * q + 1;
    float4 xv = ((const float4*)x)[node];
    float c0 = xv.x * Wi[f0] + xv.y * Wi[64 + f0] + xv.z * Wi[128 + f0] + xv.w * Wi[192 + f0];
    float c1 = xv.x * Wi[f1] + xv.y * Wi[64 + f1] + xv.z * Wi[128 + f1] + xv.w * Wi[192 + f1];
    ((unsigned*)cur)[node * 32 + q] = pkbf(fmaxf(c0, 0.f), fmaxf(c1, 0.f));
    float h0 = xv.x * We1[f0] + xv.y * We1[63 + f0] + xv.z * We1[126 + f0] + xv.w * We1[189 + f0];
    h0 = fmaxf(h0, 0.f);
    float h1 = 0.f;
    if (f1 < 63) {
        h1 = xv.x * We1[f1] + xv.y * We1[63 + f1] + xv.z * We1[126 + f1] + xv.w * We1[189 + f1];
        h1 = fmaxf(h1, 0.f);
    }
    ((unsigned*)h)[node * 32 + q] = pkbf(h0, h1);
}

// agg[n] = (1/deg) * sum src[row]   (bf16 in, fp32 accumulate, bf16 out)
// one wave per node; coalesced csr load per 64 edges; wave-uniform shuffle
// trip count (ds_bpermute from inactive lanes returns 0 -> no divergence
// around shuffles); quarter-wave group per edge, 8B bf16x4 per lane.
__global__ void k_gather(const u16* __restrict__ src, u16* __restrict__ agg,
                         const int* __restrict__ rowptr, const int* __restrict__ csr) {
    int wid = (blockIdx.x * 256 + threadIdx.x) >> 6;
    if (wid >= N_NODES) return;
    int lane = threadIdx.x & 63;
    int grp = lane >> 4;
    int fl  = (lane & 15) << 2;    // feature quad base (bf16 elems)
    int beg = rowptr[wid], end = rowptr[wid + 1];
    int deg = end - beg;
    float4 a0 = {0,0,0,0}, a1 = {0,0,0,0};
    for (int base = 0; base < deg; base += 64) {
        int cnt = min(64, deg - base);               // wave-uniform
        int r_lane = (base + lane < deg) ? csr[beg + base + lane] : 0;
        int nIter = (cnt + 15) >> 4;                 // wave-uniform trip count
        for (int it = 0; it < nIter; it++) {
            int j = it * 16 + grp;
            int ra = __shfl(r_lane, j,      64);
            int rb = __shfl(r_lane, j + 4,  64);
            int rc = __shfl(r_lane, j + 8,  64);
            int rd = __shfl(r_lane, j + 12, 64);
            if (j < cnt) {
                uint2 p = *(const uint2*)(src + (size_t)ra * 64 + fl);
                a0.x += lo2f(p.x); a0.y += hi2f(p.x); a0.z += lo2f(p.y); a0.w += hi2f(p.y);
            }
            if (j + 4 < cnt) {
                uint2 p = *(const uint2*)(src + (size_t)rb * 64 + fl);
                a1.x += lo2f(p.x); a1.y += hi2f(p.x); a1.z += lo2f(p.y); a1.w += hi2f(p.y);
            }
            if (j + 8 < cnt) {
                uint2 p = *(const uint2*)(src + (size_t)rc * 64 + fl);
                a0.x += lo2f(p.x); a0.y += hi2f(p.x); a0.z += lo2f(p.y); a0.w += hi2f(p.y);
            }
            if (j + 12 < cnt) {
                uint2 p = *(const uint2*)(src + (size_t)rd * 64 + fl);
                a1.x += lo2f(p.x); a1.y += hi2f(p.x); a1.z += lo2f(p.y); a1.w += hi2f(p.y);
            }
        }
    }
    a0.x += a1.x; a0.y += a1.y; a0.z += a1.z; a0.w += a1.w;
#pragma unroll
    for (int off = 16; off <= 32; off <<= 1) {
        a0.x += __shfl_xor(a0.x, off, 64);
        a0.y += __shfl_xor(a0.y, off, 64);
        a0.z += __shfl_xor(a0.z, off, 64);
        a0.w += __shfl_xor(a0.w, off, 64);
    }
    if (lane < 16) {
        float inv = 1.0f / (float)deg;
        uint2 o;
        o.x = pkbf(a0.x * inv, a0.y * inv);
        o.y = pkbf(a0.z * inv, a0.w * inv);
        *(uint2*)(agg + (size_t)wid * 64 + fl) = o;
    }
}

// edge_emb via MFMA: A=[agg(63,bf16) | deg/dmax], B=We2[64][64]
__global__ __launch_bounds__(256) void k_edge_mfma(
        const u16* __restrict__ agg, const int* __restrict__ deg,
        const int* __restrict__ dmax, const float* __restrict__ We2,
        u16* __restrict__ ee) {
    __shared__ unsigned SB[2][4][64][4];   // [ks][tile][slot][dw] 8KB
    int t = threadIdx.x;
    for (int F = t; F < 512; F += 256) {
        int ks = F >> 8, tile = (F >> 6) & 3, ln = F & 63;
        int c = ln & 15, q = ln >> 4;
        const float* W = We2 + (ks * 32 + q * 8) * 64 + tile * 16 + c;
        unsigned d0 = pkbf(W[0],       W[64]);
        unsigned d1 = pkbf(W[2 * 64],  W[3 * 64]);
        unsigned d2 = pkbf(W[4 * 64],  W[5 * 64]);
        unsigned d3 = pkbf(W[6 * 64],  W[7 * 64]);
        int slot = ln ^ ((ln >> 3) & 7);
        SB[ks][tile][slot][0] = d0; SB[ks][tile][slot][1] = d1;
        SB[ks][tile][slot][2] = d2; SB[ks][tile][slot][3] = d3;
    }
    __syncthreads();
    int wv = t >> 6, lane = t & 63;
    int m = lane & 15, quad = lane >> 4;
    int slot = lane ^ ((lane >> 3) & 7);
    float idm = 1.0f / (float)dmax[0];
    for (int tb = blockIdx.x * 4 + wv; tb < NTILES; tb += gridDim.x * 4) {
        int base = tb * 16;
        const u16* arow = agg + (size_t)(base + m) * 64;
        float dv = (float)deg[base + m] * idm;
        f32x4 acc[4];
#pragma unroll
        for (int i = 0; i < 4; i++) acc[i] = (f32x4){0.f, 0.f, 0.f, 0.f};
#pragma unroll
        for (int ks = 0; ks < 2; ks++) {
            bf16x8 a = *(const bf16x8*)(arow + ks * 32 + quad * 8);
            if (ks == 1 && quad == 3) a[7] = bf1(dv);   // k=63 column
#pragma unroll
            for (int tile = 0; tile < 4; tile++) {
                bf16x8 b = *(const bf16x8*)&SB[ks][tile][slot][0];
                acc[tile] = __builtin_amdgcn_mfma_f32_16x16x32_bf16(a, b, acc[tile], 0, 0, 0);
            }
        }
#pragma unroll
        for (int tile = 0; tile < 4; tile++)
#pragma unroll
            for (int r = 0; r < 4; r++)
                ee[(size_t)(base + quad * 4 + r) * 64 + tile * 16 + m] =
                    (u16)bf1(fmaxf(acc[tile][r], 0.f));
    }
}

// MPNN layer via MFMA: msg = relu([agg|ee]@Wm); out = relu([cur|msg]@Wu)
// F32OUT=false: bf16 out (consumed by gather / MFMA A-frags -> same numerics
// as rounding at the consumer). F32OUT=true (last layer): fp32 out so the
// means/readout path keeps full precision (this is what broke R8).
template <bool F32OUT>
__global__ __launch_bounds__(256) void k_layer_mfma(
        const u16* __restrict__ agg, const u16* __restrict__ ee,
        const u16* __restrict__ cur,
        const float* __restrict__ Wm, const float* __restrict__ Wu,
        void* __restrict__ outp) {
    __shared__ unsigned SB[2][4][4][64][4];   // [gemm][ks][tile][slot][dw] 32KB
    __shared__ short MT[4][16][64];           // msg bf16, swizzled f-groups, 8KB
    int t = threadIdx.x;
    for (int F = t; F < 2048; F += 256) {
        int g = F >> 10, ks = (F >> 8) & 3, tile = (F >> 6) & 3, ln = F & 63;
        int c = ln & 15, q = ln >> 4;
        const float* W = (g ? Wu : Wm) + (ks * 32 + q * 8) * 64 + tile * 16 + c;
        unsigned d0 = pkbf(W[0],      W[64]);
        unsigned d1 = pkbf(W[2 * 64], W[3 * 64]);
        unsigned d2 = pkbf(W[4 * 64], W[5 * 64]);
        unsigned d3 = pkbf(W[6 * 64], W[7 * 64]);
        int slot = ln ^ ((ln >> 3) & 7);
        SB[g][ks][tile][slot][0] = d0; SB[g][ks][tile][slot][1] = d1;
        SB[g][ks][tile][slot][2] = d2; SB[g][ks][tile][slot][3] = d3;
    }
    __syncthreads();
    int wv = t >> 6, lane = t & 63;
    int m = lane & 15, quad = lane >> 4;
    int slot = lane ^ ((lane >> 3) & 7);
    for (int tb = blockIdx.x * 4 + wv; tb < NTILES; tb += gridDim.x * 4) {
        int base = tb * 16;
        const u16* arow = agg + (size_t)(base + m) * 64;
        const u16* erow = ee  + (size_t)(base + m) * 64;
        const u16* crow = cur + (size_t)(base + m) * 64;
        f32x4 acc[4];
#pragma unroll
        for (int i = 0; i < 4; i++) acc[i] = (f32x4){0.f, 0.f, 0.f, 0.f};
        // GEMM1: k 0..63 = agg, 64..127 = ee
#pragma unroll
        for (int ks = 0; ks < 4; ks++) {
            const u16* src = (ks < 2) ? (arow + ks * 32) : (erow + (ks - 2) * 32);
            bf16x8 a = *(const bf16x8*)(src + quad * 8);
#pragma unroll
            for (int tile = 0; tile < 4; tile++) {
                bf16x8 b = *(const bf16x8*)&SB[0][ks][tile][slot][0];
                acc[tile] = __builtin_amdgcn_mfma_f32_16x16x32_bf16(a, b, acc[tile], 0, 0, 0);
            }
        }
        // relu(msg) -> MT in A-readable swizzled layout (wave-private, no barrier)
#pragma unroll
        for (int tile = 0; tile < 4; tile++)
#pragma unroll
            for (int r = 0; r < 4; r++) {
                int node = quad * 4 + r;
                int f = tile * 16 + m;
                int sidx = (((f >> 3) ^ (node & 7)) << 3) | (f & 7);
                MT[wv][node][sidx] = bf1(fmaxf(acc[tile][r], 0.f));
            }
        // GEMM2: k 0..63 = cur (global bf16), 64..127 = msg (LDS)
#pragma unroll
        for (int i = 0; i < 4; i++) acc[i] = (f32x4){0.f, 0.f, 0.f, 0.f};
#pragma unroll
        for (int ks = 0; ks < 4; ks++) {
            bf16x8 a;
            if (ks < 2) {
                a = *(const bf16x8*)(crow + ks * 32 + quad * 8);
            } else {
                int gp = ((ks - 2) * 4 + quad) ^ (m & 7);
                a = *(const bf16x8*)&MT[wv][m][gp << 3];
            }
#pragma unroll
            for (int tile = 0; tile < 4; tile++) {
                bf16x8 b = *(const bf16x8*)&SB[1][ks][tile][slot][0];
                acc[tile] = __builtin_amdgcn_mfma_f32_16x16x32_bf16(a, b, acc[tile], 0, 0, 0);
            }
        }
#pragma unroll
        for (int tile = 0; tile < 4; tile++)
#pragma unroll
            for (int r = 0; r < 4; r++) {
                float v = fmaxf(acc[tile][r], 0.f);
                size_t oi = (size_t)(base + quad * 4 + r) * 64 + tile * 16 + m;
                if (F32OUT) ((float*)outp)[oi] = v;
                else        ((u16*)outp)[oi] = (u16)bf1(v);
            }
    }
}

// per-graph mean of cur (fp32 final layer); 20 blocks/graph
__global__ void k_means(const float* __restrict__ cur, float* __restrict__ means) {
    int g = blockIdx.x / MCHUNK;
    int c = blockIdx.x % MCHUNK;
    int t = threadIdx.x, f = t & 63, q = t >> 6;
    int base = g * NPG + c * MROWS;
    float acc = 0.f;
    for (int n = base + q; n < base + MROWS; n += 4) acc += cur[(size_t)n * 64 + f];
    __shared__ float red[4][64];
    red[q][f] = acc;
    __syncthreads();
    if (q == 0)
        atomicAdd(&means[g * 64 + f],
                  (red[0][f] + red[1][f] + red[2][f] + red[3][f]) * (1.0f / NPG));
}

// r1[g] = sum_f relu((means[g] @ Wp)[f]) * Wr[f]  -- 50 graphs, 1 block
__global__ __launch_bounds__(256) void k_pool(
        const float* __restrict__ means, const float* __restrict__ Wp,
        const float* __restrict__ Wr, float* __restrict__ r1) {
    int wv = threadIdx.x >> 6, lane = threadIdx.x & 63;
    for (int g = wv; g < NG; g += 4) {
        float acc = 0.f;
#pragma unroll 16
        for (int k = 0; k < 64; k++) acc = fmaf(means[g * 64 + k], Wp[k * 64 + lane], acc);
        float v = fmaxf(acc, 0.f) * Wr[lane];
        for (int off = 32; off; off >>= 1) v += __shfl_xor(v, off, 64);
        if (lane == 0) r1[g] = v;
    }
}

// out[n] = b + r1[batch[n]] + dot(relu(cur[n]), Wr[64:])  -- quarter-wave per node
__global__ void k_read2(const float* __restrict__ cur, const float* __restrict__ r1,
                        const int* __restrict__ batch, const float* __restrict__ Wr,
                        const float* __restrict__ br, float* __restrict__ out) {
    int idx = blockIdx.x * 256 + threadIdx.x;
    int node = idx >> 4;
    if (node >= N_NODES) return;
    int q = idx & 15;
    float4 c = *(const float4*)(cur + (size_t)node * 64 + q * 4);
    float4 w = *(const float4*)(Wr + 64 + q * 4);
    float v = fmaxf(c.x, 0.f) * w.x + fmaxf(c.y, 0.f) * w.y
            + fmaxf(c.z, 0.f) * w.z + fmaxf(c.w, 0.f) * w.w;
    v += __shfl_xor(v, 1, 64); v += __shfl_xor(v, 2, 64);
    v += __shfl_xor(v, 4, 64); v += __shfl_xor(v, 8, 64);
    if (q == 0) out[node] = v + r1[batch[node]] + br[0];
}

// ---------------------------------------------------------------------------
extern "C" void kernel_launch(void* const* d_in, const int* in_sizes, int n_in,
                              void* d_out, int out_size, void* d_ws, size_t ws_size,
                              hipStream_t stream) {
    const float* x    = (const float*)d_in[0];
    const float* Wi   = (const float*)d_in[1];
    const float* We1  = (const float*)d_in[2];
    const float* We2  = (const float*)d_in[3];
    const float* Wm   = (const float*)d_in[4];   // [3,128,64]
    const float* Wu   = (const float*)d_in[5];   // [3,128,64]
    const float* Wp   = (const float*)d_in[6];
    const float* Wr   = (const float*)d_in[7];
    const float* br   = (const float*)d_in[8];
    const int*   ei   = (const int*)d_in[9];     // [2,E]
    const int*   batch= (const int*)d_in[10];
    const int* row = ei;
    const int* col = ei + N_EDGES;
    float* out = (float*)d_out;

    char* w = (char*)d_ws;
    size_t off = 0;
    auto carve = [&](size_t bytes) -> void* {
        void* p = (void*)(w + off);
        off += (bytes + 255) & ~(size_t)255;
        return p;
    };
    int*   deg      = (int*)carve((size_t)N_NODES * 4);
    int*   rowptr   = (int*)carve((size_t)(N_NODES + 1) * 4);
    int*   cursor   = (int*)carve((size_t)N_NODES * 4);
    int*   csr      = (int*)carve((size_t)N_EDGES * 4);
    int*   partials = (int*)carve((size_t)SCAN_NBLK * 4);
    u16*   bufA     = (u16*)carve((size_t)N_NODES * 64 * 2);
    u16*   bufB     = (u16*)carve((size_t)N_NODES * 64 * 2);
    u16*   agg      = (u16*)carve((size_t)N_NODES * 64 * 2);
    u16*   ee       = (u16*)carve((size_t)N_NODES * 64 * 2);
    float* curF     = (float*)carve((size_t)N_NODES * 64 * 4);
    float* means    = (float*)carve((size_t)NG * 64 * 4);
    float* r1       = (float*)carve((size_t)NG * 4);
    int*   dmax     = (int*)carve(256);

    hipMemsetAsync(deg,   0, (size_t)N_NODES * 4, stream);
    hipMemsetAsync(dmax,  0, 4, stream);
    hipMemsetAsync(means, 0, (size_t)NG * 64 * 4, stream);

    k_deg         <<<FP_CHUNKS * 8, 256, 0, stream>>>(col, deg);
    k_blocksum    <<<SCAN_NBLK, 256, 0, stream>>>(deg, partials, dmax);
    k_scanpartials<<<1, 256, 0, stream>>>(partials, rowptr);
    k_scanfinal   <<<SCAN_NBLK, 256, 0, stream>>>(deg, partials, rowptr, cursor);
    k_fill        <<<FP_CHUNKS * 8, 256, 0, stream>>>(row, col, cursor, csr);

    k_init  <<<(N_NODES * 32 + 255) / 256, 256, 0, stream>>>(x, Wi, We1, bufA, bufB);

    // bufB = h
    k_gather<<<(N_NODES * 64 + 255) / 256, 256, 0, stream>>>(bufB, agg, rowptr, csr);
    k_edge_mfma<<<392, 256, 0, stream>>>(agg, deg, dmax, We2, ee);

    // layer 0: cur=bufA -> bufB (bf16)
    k_gather<<<(N_NODES * 64 + 255) / 256, 256, 0, stream>>>(bufA, agg, rowptr, csr);
    k_layer_mfma<false><<<392, 256, 0, stream>>>(agg, ee, bufA, Wm, Wu, bufB);
    // layer 1: cur=bufB -> bufA (bf16)
    k_gather<<<(N_NODES * 64 + 255) / 256, 256, 0, stream>>>(bufB, agg, rowptr, csr);
    k_layer_mfma<false><<<392, 256, 0, stream>>>(agg, ee, bufB,
                                                 Wm + 128 * 64, Wu + 128 * 64, bufA);
    // layer 2 (last): cur=bufA -> curF (fp32, full-precision readout path)
    k_gather<<<(N_NODES * 64 + 255) / 256, 256, 0, stream>>>(bufA, agg, rowptr, csr);
    k_layer_mfma<true><<<392, 256, 0, stream>>>(agg, ee, bufA,
                                                Wm + 2 * 128 * 64, Wu + 2 * 128 * 64, curF);

    k_means<<<NG * MCHUNK, 256, 0, stream>>>(curF, means);
    k_pool <<<1, 256, 0, stream>>>(means, Wp, Wr, r1);
    k_read2<<<(N_NODES * 16 + 255) / 256, 256, 0, stream>>>(curF, r1, batch, Wr, br, out);
}